// Round 2
// baseline (7549.644 us; speedup 1.0000x reference)
//
#include <hip/hip_runtime.h>
#include <hip/hip_bf16.h>
#include <math.h>

// Problem constants
#define D_MODEL 2048
#define N_H     16
#define D_H     128
#define D_CQ    768
#define D_CKV   512
#define D_HR    64
#define SEQ     2048

// ---------------------------------------------------------------------------
// RMSNorm: h[s][d] = x[s][d] * rsqrt(mean(x[s]^2) + eps) * w[d]
// one block per row, 256 threads
// ---------------------------------------------------------------------------
__global__ __launch_bounds__(256) void rmsnorm_kernel(
    const float* __restrict__ x, const float* __restrict__ w, float* __restrict__ h) {
  int row = blockIdx.x;
  int tid = threadIdx.x;
  const float* xr = x + (size_t)row * D_MODEL;
  float ss = 0.f;
  for (int i = tid; i < D_MODEL; i += 256) { float v = xr[i]; ss += v * v; }
  __shared__ float red[256];
  red[tid] = ss;
  __syncthreads();
  for (int s = 128; s > 0; s >>= 1) {
    if (tid < s) red[tid] += red[tid + s];
    __syncthreads();
  }
  float scale = rsqrtf(red[0] / (float)D_MODEL + 1.1920929e-7f);
  float* hr = h + (size_t)row * D_MODEL;
  for (int i = tid; i < D_MODEL; i += 256) hr[i] = xr[i] * scale * w[i];
}

// ---------------------------------------------------------------------------
// Tiled f32 GEMM: C[M,N] = A[M,K] @ B[K,N] (+ addv elementwise, optional)
// All row-major. M,N multiples of 64; K multiple of 16.
// 64x64 tile, BK=16, 256 threads, 4x4 microtile per thread.
// ---------------------------------------------------------------------------
#define BM 64
#define BN 64
#define BK 16

__global__ __launch_bounds__(256) void gemm_f32(
    const float* __restrict__ A, const float* __restrict__ B,
    float* __restrict__ C, const float* __restrict__ addv,
    int M, int N, int K) {
  __shared__ float As[BK][BM + 4];  // +4 pad keeps float4 alignment, breaks conflicts
  __shared__ float Bs[BK][BN + 4];
  int tid = threadIdx.x;
  int bm = blockIdx.y * BM, bn = blockIdx.x * BN;
  int tm = (tid >> 4) << 2;   // 0..60 step 4
  int tn = (tid & 15) << 2;   // 0..60 step 4
  float acc[4][4] = {};

  for (int k0 = 0; k0 < K; k0 += BK) {
#pragma unroll
    for (int i = 0; i < 4; i++) {          // A tile: 64 rows x 16 k
      int idx = tid + i * 256;
      int r = idx >> 4, c = idx & 15;
      As[c][r] = A[(size_t)(bm + r) * K + k0 + c];
    }
#pragma unroll
    for (int i = 0; i < 4; i++) {          // B tile: 16 k x 64 cols
      int idx = tid + i * 256;
      int r = idx >> 6, c = idx & 63;
      Bs[r][c] = B[(size_t)(k0 + r) * N + bn + c];
    }
    __syncthreads();
#pragma unroll
    for (int kk = 0; kk < BK; kk++) {
      float4 a4 = *(const float4*)&As[kk][tm];
      float4 b4 = *(const float4*)&Bs[kk][tn];
      float av[4] = {a4.x, a4.y, a4.z, a4.w};
      float bv[4] = {b4.x, b4.y, b4.z, b4.w};
#pragma unroll
      for (int i = 0; i < 4; i++)
#pragma unroll
        for (int j = 0; j < 4; j++) acc[i][j] += av[i] * bv[j];
    }
    __syncthreads();
  }

#pragma unroll
  for (int i = 0; i < 4; i++) {
    size_t row = bm + tm + i;
    size_t off = row * N + bn + tn;
    float4 vout = make_float4(acc[i][0], acc[i][1], acc[i][2], acc[i][3]);
    if (addv) {
      float4 a4 = *(const float4*)&addv[off];
      vout.x += a4.x; vout.y += a4.y; vout.z += a4.z; vout.w += a4.w;
    }
    *(float4*)&C[off] = vout;
  }
}

// ---------------------------------------------------------------------------
// RoPE (interleaved pairs), in-place.
// q_r: (SEQ, N_H, 64)  -> one thread per pair, pos = s
// k_r: (SEQ, 64)       -> one thread per pair, pos = s
// ---------------------------------------------------------------------------
__global__ void rope_q_kernel(float* __restrict__ qr) {
  int idx = blockIdx.x * blockDim.x + threadIdx.x;  // SEQ*N_H*32 total
  if (idx >= SEQ * N_H * 32) return;
  int j = idx & 31;
  int rest = idx >> 5;           // s*N_H + h
  int s = rest >> 4;
  float* p = qr + (size_t)rest * 64 + 2 * j;
  float inv = expf(-((float)(2 * j) / 64.0f) * logf(10000.0f));
  float ang = (float)s * inv;
  float c = cosf(ang), sn = sinf(ang);
  float x0 = p[0], x1 = p[1];
  p[0] = x0 * c - x1 * sn;
  p[1] = x0 * sn + x1 * c;
}

__global__ void rope_k_kernel(float* __restrict__ kr) {
  int idx = blockIdx.x * blockDim.x + threadIdx.x;  // SEQ*32 total
  if (idx >= SEQ * 32) return;
  int j = idx & 31;
  int s = idx >> 5;
  float* p = kr + (size_t)s * 64 + 2 * j;
  float inv = expf(-((float)(2 * j) / 64.0f) * logf(10000.0f));
  float ang = (float)s * inv;
  float c = cosf(ang), sn = sinf(ang);
  float x0 = p[0], x1 = p[1];
  p[0] = x0 * c - x1 * sn;
  p[1] = x0 * sn + x1 * c;
}

// ---------------------------------------------------------------------------
// Causal attention, one block per (query row, head).
// q = [qc(128) | qr(64)], k = [kc(128) | kr(64)], scale = 1/sqrt(192)
// Scores for k<=qi staged in LDS; softmax via block reductions; PV with
// lane-per-dim (coalesced V reads). Output layout (s, h*128+d).
// ---------------------------------------------------------------------------
__global__ __launch_bounds__(256) void attn_kernel(
    const float* __restrict__ qc, const float* __restrict__ qr,
    const float* __restrict__ kc, const float* __restrict__ kr,
    const float* __restrict__ v, float* __restrict__ out) {
  int qi = blockIdx.x;
  int h  = blockIdx.y;
  int tid = threadIdx.x;

  __shared__ float qv[192];
  __shared__ float sc[SEQ];
  __shared__ float red[256];

  if (tid < 128)      qv[tid] = qc[(size_t)qi * (N_H * D_H) + h * D_H + tid];
  else if (tid < 192) qv[tid] = qr[(size_t)qi * (N_H * D_HR) + h * D_HR + (tid - 128)];
  __syncthreads();

  const float scale = 7.2168784e-02f;  // 1/sqrt(192)
  float lmax = -1e30f;
  for (int k = tid; k <= qi; k += 256) {
    const float* kcp = kc + (size_t)k * (N_H * D_H) + h * D_H;
    const float* krp = kr + (size_t)k * D_HR;
    float s = 0.f;
#pragma unroll 4
    for (int d = 0; d < 128; d++) s += qv[d] * kcp[d];
#pragma unroll 4
    for (int d = 0; d < 64; d++) s += qv[128 + d] * krp[d];
    s *= scale;
    sc[k] = s;
    lmax = fmaxf(lmax, s);
  }
  red[tid] = lmax;
  __syncthreads();
  for (int st = 128; st > 0; st >>= 1) {
    if (tid < st) red[tid] = fmaxf(red[tid], red[tid + st]);
    __syncthreads();
  }
  float m = red[0];
  __syncthreads();

  float lsum = 0.f;
  for (int k = tid; k <= qi; k += 256) {
    float p = expf(sc[k] - m);
    sc[k] = p;
    lsum += p;
  }
  red[tid] = lsum;
  __syncthreads();
  for (int st = 128; st > 0; st >>= 1) {
    if (tid < st) red[tid] += red[tid + st];
    __syncthreads();
  }
  float l = red[0];
  __syncthreads();

  // PV: lanes 0..127 handle dim d for even k, 128..255 same dims, odd k
  int d = tid & 127, half = tid >> 7;
  float acc = 0.f;
  for (int k = half; k <= qi; k += 2)
    acc += sc[k] * v[(size_t)k * (N_H * D_H) + h * D_H + d];
  red[tid] = acc;
  __syncthreads();
  if (tid < 128)
    out[(size_t)qi * (N_H * D_H) + h * D_H + tid] = (red[tid] + red[tid + 128]) / l;
}

// ---------------------------------------------------------------------------
extern "C" void kernel_launch(void* const* d_in, const int* in_sizes, int n_in,
                              void* d_out, int out_size, void* d_ws, size_t ws_size,
                              hipStream_t stream) {
  const float* x      = (const float*)d_in[0];
  // d_in[1] = mask: causal triu, handled structurally — not read.
  const float* w_norm = (const float*)d_in[2];
  const float* w_cq   = (const float*)d_in[3];
  const float* w_q    = (const float*)d_in[4];
  const float* w_qr   = (const float*)d_in[5];
  const float* w_ckv  = (const float*)d_in[6];
  const float* w_k    = (const float*)d_in[7];
  const float* w_kr   = (const float*)d_in[8];
  const float* w_v    = (const float*)d_in[9];
  const float* w_o    = (const float*)d_in[10];
  float* out = (float*)d_out;

  float* ws = (float*)d_ws;
  float* h    = ws;                         // 2048*2048
  float* c_q  = h    + (size_t)SEQ * D_MODEL;      // 2048*768
  float* c_kv = c_q  + (size_t)SEQ * D_CQ;         // 2048*512
  float* k_r  = c_kv + (size_t)SEQ * D_CKV;        // 2048*64
  float* q_c  = k_r  + (size_t)SEQ * D_HR;         // 2048*2048
  float* q_r  = q_c  + (size_t)SEQ * (N_H * D_H);  // 2048*1024
  float* k_c  = q_r  + (size_t)SEQ * (N_H * D_HR); // 2048*2048
  float* vbuf = k_c  + (size_t)SEQ * (N_H * D_H);  // 2048*2048
  float* ao   = vbuf + (size_t)SEQ * (N_H * D_H);  // 2048*2048

  // 1. h = rmsnorm(x) * w_norm
  rmsnorm_kernel<<<SEQ, 256, 0, stream>>>(x, w_norm, h);

  // 2. c_q = h @ w_cq           (2048x2048 · 2048x768)
  gemm_f32<<<dim3(D_CQ / BN, SEQ / BM), 256, 0, stream>>>(h, w_cq, c_q, nullptr, SEQ, D_CQ, D_MODEL);
  // 3. c_kv = h @ w_ckv         (2048x2048 · 2048x512)
  gemm_f32<<<dim3(D_CKV / BN, SEQ / BM), 256, 0, stream>>>(h, w_ckv, c_kv, nullptr, SEQ, D_CKV, D_MODEL);
  // 4. k_r = rope(h @ w_kr)     (2048x2048 · 2048x64)
  gemm_f32<<<dim3(D_HR / BN, SEQ / BM), 256, 0, stream>>>(h, w_kr, k_r, nullptr, SEQ, D_HR, D_MODEL);
  rope_k_kernel<<<(SEQ * 32 + 255) / 256, 256, 0, stream>>>(k_r);

  // 5. q_c = c_q @ w_q          (2048x768 · 768x2048)
  gemm_f32<<<dim3((N_H * D_H) / BN, SEQ / BM), 256, 0, stream>>>(c_q, w_q, q_c, nullptr, SEQ, N_H * D_H, D_CQ);
  // 6. q_r = rope(c_q @ w_qr)   (2048x768 · 768x1024)
  gemm_f32<<<dim3((N_H * D_HR) / BN, SEQ / BM), 256, 0, stream>>>(c_q, w_qr, q_r, nullptr, SEQ, N_H * D_HR, D_CQ);
  rope_q_kernel<<<(SEQ * N_H * 32 + 255) / 256, 256, 0, stream>>>(q_r);

  // 7. k_c = c_kv @ w_k         (2048x512 · 512x2048)
  gemm_f32<<<dim3((N_H * D_H) / BN, SEQ / BM), 256, 0, stream>>>(c_kv, w_k, k_c, nullptr, SEQ, N_H * D_H, D_CKV);
  // 8. v = c_kv @ w_v           (2048x512 · 512x2048)
  gemm_f32<<<dim3(D_MODEL / BN, SEQ / BM), 256, 0, stream>>>(c_kv, w_v, vbuf, nullptr, SEQ, D_MODEL, D_CKV);

  // 9. attention -> ao (s, h*128+d)
  attn_kernel<<<dim3(SEQ, N_H), 256, 0, stream>>>(q_c, q_r, k_c, k_r, vbuf, ao);

  // 10. out = ao @ w_o + x      (2048x2048 · 2048x2048)
  gemm_f32<<<dim3(D_MODEL / BN, SEQ / BM), 256, 0, stream>>>(ao, w_o, out, x, SEQ, D_MODEL, D_MODEL);
}

// Round 3
// 3687.148 us; speedup vs baseline: 2.0476x; 2.0476x over previous
//
#include <hip/hip_runtime.h>
#include <hip/hip_bf16.h>
#include <math.h>

// Problem constants
#define D_MODEL 2048
#define N_H     16
#define D_H     128
#define D_CQ    768
#define D_CKV   512
#define D_HR    64
#define SEQ     2048

// ---------------------------------------------------------------------------
// RMSNorm: h[s][d] = x[s][d] * rsqrt(mean(x[s]^2) + eps) * w[d]
// ---------------------------------------------------------------------------
__global__ __launch_bounds__(256) void rmsnorm_kernel(
    const float* __restrict__ x, const float* __restrict__ w, float* __restrict__ h) {
  int row = blockIdx.x;
  int tid = threadIdx.x;
  const float* xr = x + (size_t)row * D_MODEL;
  float ss = 0.f;
  for (int i = tid; i < D_MODEL; i += 256) { float v = xr[i]; ss += v * v; }
  __shared__ float red[256];
  red[tid] = ss;
  __syncthreads();
  for (int s = 128; s > 0; s >>= 1) {
    if (tid < s) red[tid] += red[tid + s];
    __syncthreads();
  }
  float scale = rsqrtf(red[0] / (float)D_MODEL + 1.1920929e-7f);
  float* hr = h + (size_t)row * D_MODEL;
  for (int i = tid; i < D_MODEL; i += 256) hr[i] = xr[i] * scale * w[i];
}

// ---------------------------------------------------------------------------
// Tiled f32 GEMM: C[M,N] = A[M,K] @ B[K,N] (+ addv elementwise, optional)
// ---------------------------------------------------------------------------
#define BM 64
#define BN 64
#define BK 16

__global__ __launch_bounds__(256) void gemm_f32(
    const float* __restrict__ A, const float* __restrict__ B,
    float* __restrict__ C, const float* __restrict__ addv,
    int M, int N, int K) {
  __shared__ float As[BK][BM + 4];
  __shared__ float Bs[BK][BN + 4];
  int tid = threadIdx.x;
  int bm = blockIdx.y * BM, bn = blockIdx.x * BN;
  int tm = (tid >> 4) << 2;
  int tn = (tid & 15) << 2;
  float acc[4][4] = {};

  for (int k0 = 0; k0 < K; k0 += BK) {
#pragma unroll
    for (int i = 0; i < 4; i++) {
      int idx = tid + i * 256;
      int r = idx >> 4, c = idx & 15;
      As[c][r] = A[(size_t)(bm + r) * K + k0 + c];
    }
#pragma unroll
    for (int i = 0; i < 4; i++) {
      int idx = tid + i * 256;
      int r = idx >> 6, c = idx & 63;
      Bs[r][c] = B[(size_t)(k0 + r) * N + bn + c];
    }
    __syncthreads();
#pragma unroll
    for (int kk = 0; kk < BK; kk++) {
      float4 a4 = *(const float4*)&As[kk][tm];
      float4 b4 = *(const float4*)&Bs[kk][tn];
      float av[4] = {a4.x, a4.y, a4.z, a4.w};
      float bv[4] = {b4.x, b4.y, b4.z, b4.w};
#pragma unroll
      for (int i = 0; i < 4; i++)
#pragma unroll
        for (int j = 0; j < 4; j++) acc[i][j] += av[i] * bv[j];
    }
    __syncthreads();
  }

#pragma unroll
  for (int i = 0; i < 4; i++) {
    size_t row = bm + tm + i;
    size_t off = row * N + bn + tn;
    float4 vout = make_float4(acc[i][0], acc[i][1], acc[i][2], acc[i][3]);
    if (addv) {
      float4 a4 = *(const float4*)&addv[off];
      vout.x += a4.x; vout.y += a4.y; vout.z += a4.z; vout.w += a4.w;
    }
    *(float4*)&C[off] = vout;
  }
}

// ---------------------------------------------------------------------------
// RoPE (interleaved pairs), in-place.
// ---------------------------------------------------------------------------
__global__ void rope_q_kernel(float* __restrict__ qr) {
  int idx = blockIdx.x * blockDim.x + threadIdx.x;
  if (idx >= SEQ * N_H * 32) return;
  int j = idx & 31;
  int rest = idx >> 5;
  int s = rest >> 4;
  float* p = qr + (size_t)rest * 64 + 2 * j;
  float inv = expf(-((float)(2 * j) / 64.0f) * logf(10000.0f));
  float ang = (float)s * inv;
  float c = cosf(ang), sn = sinf(ang);
  float x0 = p[0], x1 = p[1];
  p[0] = x0 * c - x1 * sn;
  p[1] = x0 * sn + x1 * c;
}

__global__ void rope_k_kernel(float* __restrict__ kr) {
  int idx = blockIdx.x * blockDim.x + threadIdx.x;
  if (idx >= SEQ * 32) return;
  int j = idx & 31;
  int s = idx >> 5;
  float* p = kr + (size_t)s * 64 + 2 * j;
  float inv = expf(-((float)(2 * j) / 64.0f) * logf(10000.0f));
  float ang = (float)s * inv;
  float c = cosf(ang), sn = sinf(ang);
  float x0 = p[0], x1 = p[1];
  p[0] = x0 * c - x1 * sn;
  p[1] = x0 * sn + x1 * c;
}

// ---------------------------------------------------------------------------
// Flash-style causal attention. One block per (head, 64-query tile).
// Iterates 64-key tiles up to the causal diagonal. S=QK^T via 4x4 microtile
// GEMM with d-chunked LDS staging; online softmax with in-wave shfl_xor row
// reductions (rows live entirely on the 16 tx lanes of one wave); P staged
// transposed (Ps[k][q]) so PV reads are float4; O columns interleaved
// (tx+16j) for conflict-free V reads and coalesced epilogue stores.
// ---------------------------------------------------------------------------
#define AQ 64
#define AK 64
#define AD 32

__global__ __launch_bounds__(256) void attn_flash(
    const float* __restrict__ qc, const float* __restrict__ qr,
    const float* __restrict__ kc, const float* __restrict__ kr,
    const float* __restrict__ v, float* __restrict__ out) {
  int h = blockIdx.y;
  // reverse so heaviest (largest q0) tiles launch first — load balance
  int q0 = ((int)gridDim.x - 1 - (int)blockIdx.x) * AQ;
  int tid = threadIdx.x;
  int tx = tid & 15, ty = tid >> 4;

  __shared__ float Qs[AD][AQ + 4];     // [d][q]
  __shared__ float Ks[AD][AK + 4];     // [d][k]
  __shared__ float Ps[AK][AQ + 4];     // P transposed: [k][q]
  __shared__ float Vs[16][128 + 4];    // [k-chunk][dim]

  float O[4][8];
  float m_run[4], l_run[4];
#pragma unroll
  for (int i = 0; i < 4; i++) {
    m_run[i] = -1e30f;
    l_run[i] = 0.f;
#pragma unroll
    for (int j = 0; j < 8; j++) O[i][j] = 0.f;
  }
  const float scale = 0.07216878364870323f;  // 1/sqrt(192)

  for (int k0 = 0; k0 < q0 + AQ; k0 += AK) {
    float S[4][4] = {};
    // ---- S = Q @ K^T over d chunks ----
    for (int d0 = 0; d0 < 192; d0 += AD) {
#pragma unroll
      for (int i = 0; i < 8; i++) {
        int idx = tid + i * 256;
        int r = idx >> 5, c = idx & 31;   // 64 rows x 32 dims
        int d = d0 + c;
        float qv = (d < 128) ? qc[(size_t)(q0 + r) * (N_H * D_H) + h * D_H + d]
                             : qr[(size_t)(q0 + r) * (N_H * D_HR) + h * D_HR + (d - 128)];
        Qs[c][r] = qv;
        float kv = (d < 128) ? kc[(size_t)(k0 + r) * (N_H * D_H) + h * D_H + d]
                             : kr[(size_t)(k0 + r) * D_HR + (d - 128)];
        Ks[c][r] = kv;
      }
      __syncthreads();
#pragma unroll
      for (int dd = 0; dd < AD; dd++) {
        float4 a4 = *(const float4*)&Qs[dd][ty * 4];
        float4 b4 = *(const float4*)&Ks[dd][tx * 4];
        float av[4] = {a4.x, a4.y, a4.z, a4.w};
        float bv[4] = {b4.x, b4.y, b4.z, b4.w};
#pragma unroll
        for (int i = 0; i < 4; i++)
#pragma unroll
          for (int j = 0; j < 4; j++) S[i][j] += av[i] * bv[j];
      }
      __syncthreads();
    }

    // ---- scale + causal mask + online softmax (in-wave row reductions) ----
#pragma unroll
    for (int i = 0; i < 4; i++) {
      int row = q0 + ty * 4 + i;
      float mm = m_run[i];
#pragma unroll
      for (int j = 0; j < 4; j++) {
        int col = k0 + tx * 4 + j;
        S[i][j] = (col <= row) ? S[i][j] * scale : -1e30f;
        mm = fmaxf(mm, S[i][j]);
      }
      // butterfly max across the 16 tx lanes (row is wave-local)
#pragma unroll
      for (int off = 1; off < 16; off <<= 1)
        mm = fmaxf(mm, __shfl_xor(mm, off, 64));
      float alpha = __builtin_expf(m_run[i] - mm);
      m_run[i] = mm;
      float ps = 0.f;
#pragma unroll
      for (int j = 0; j < 4; j++) {
        S[i][j] = __builtin_expf(S[i][j] - mm);
        ps += S[i][j];
      }
#pragma unroll
      for (int off = 1; off < 16; off <<= 1)
        ps += __shfl_xor(ps, off, 64);
      l_run[i] = l_run[i] * alpha + ps;
#pragma unroll
      for (int j = 0; j < 8; j++) O[i][j] *= alpha;
    }

    // ---- stage P transposed: Ps[k][q] (float4 along q) ----
    __syncthreads();  // prior PV reads of Ps done (sync at end of last chunk covers 1st iter)
#pragma unroll
    for (int j = 0; j < 4; j++) {
      float4 pv = make_float4(S[0][j], S[1][j], S[2][j], S[3][j]);
      *(float4*)&Ps[tx * 4 + j][ty * 4] = pv;
    }
    __syncthreads();

    // ---- O += P @ V, keys in chunks of 16 ----
    for (int kk0 = 0; kk0 < AK; kk0 += 16) {
#pragma unroll
      for (int i = 0; i < 8; i++) {
        int idx = tid + i * 256;
        int r = idx >> 7, c = idx & 127;  // 16 keys x 128 dims
        Vs[r][c] = v[(size_t)(k0 + kk0 + r) * (N_H * D_H) + h * D_H + c];
      }
      __syncthreads();
#pragma unroll
      for (int t = 0; t < 16; t++) {
        float4 p4 = *(const float4*)&Ps[kk0 + t][ty * 4];
        float pv[4] = {p4.x, p4.y, p4.z, p4.w};
#pragma unroll
        for (int j = 0; j < 8; j++) {
          float vv = Vs[t][tx + 16 * j];
#pragma unroll
          for (int i = 0; i < 4; i++) O[i][j] += pv[i] * vv;
        }
      }
      __syncthreads();
    }
  }

  // ---- epilogue: out[q][h*128 + d], d = tx + 16j (coalesced 16-float runs) ----
#pragma unroll
  for (int i = 0; i < 4; i++) {
    int row = q0 + ty * 4 + i;
    float inv_l = 1.0f / l_run[i];
#pragma unroll
    for (int j = 0; j < 8; j++)
      out[(size_t)row * (N_H * D_H) + h * D_H + tx + 16 * j] = O[i][j] * inv_l;
  }
}

// ---------------------------------------------------------------------------
extern "C" void kernel_launch(void* const* d_in, const int* in_sizes, int n_in,
                              void* d_out, int out_size, void* d_ws, size_t ws_size,
                              hipStream_t stream) {
  const float* x      = (const float*)d_in[0];
  // d_in[1] = mask: causal triu, handled structurally — not read.
  const float* w_norm = (const float*)d_in[2];
  const float* w_cq   = (const float*)d_in[3];
  const float* w_q    = (const float*)d_in[4];
  const float* w_qr   = (const float*)d_in[5];
  const float* w_ckv  = (const float*)d_in[6];
  const float* w_k    = (const float*)d_in[7];
  const float* w_kr   = (const float*)d_in[8];
  const float* w_v    = (const float*)d_in[9];
  const float* w_o    = (const float*)d_in[10];
  float* out = (float*)d_out;

  float* ws = (float*)d_ws;
  float* h    = ws;                                // 2048*2048
  float* c_q  = h    + (size_t)SEQ * D_MODEL;      // 2048*768
  float* c_kv = c_q  + (size_t)SEQ * D_CQ;         // 2048*512
  float* k_r  = c_kv + (size_t)SEQ * D_CKV;        // 2048*64
  float* q_c  = k_r  + (size_t)SEQ * D_HR;         // 2048*2048
  float* q_r  = q_c  + (size_t)SEQ * (N_H * D_H);  // 2048*1024
  float* k_c  = q_r  + (size_t)SEQ * (N_H * D_HR); // 2048*2048
  float* vbuf = k_c  + (size_t)SEQ * (N_H * D_H);  // 2048*2048
  float* ao   = vbuf + (size_t)SEQ * (N_H * D_H);  // 2048*2048

  rmsnorm_kernel<<<SEQ, 256, 0, stream>>>(x, w_norm, h);

  gemm_f32<<<dim3(D_CQ / BN, SEQ / BM), 256, 0, stream>>>(h, w_cq, c_q, nullptr, SEQ, D_CQ, D_MODEL);
  gemm_f32<<<dim3(D_CKV / BN, SEQ / BM), 256, 0, stream>>>(h, w_ckv, c_kv, nullptr, SEQ, D_CKV, D_MODEL);
  gemm_f32<<<dim3(D_HR / BN, SEQ / BM), 256, 0, stream>>>(h, w_kr, k_r, nullptr, SEQ, D_HR, D_MODEL);
  rope_k_kernel<<<(SEQ * 32 + 255) / 256, 256, 0, stream>>>(k_r);

  gemm_f32<<<dim3((N_H * D_H) / BN, SEQ / BM), 256, 0, stream>>>(c_q, w_q, q_c, nullptr, SEQ, N_H * D_H, D_CQ);
  gemm_f32<<<dim3((N_H * D_HR) / BN, SEQ / BM), 256, 0, stream>>>(c_q, w_qr, q_r, nullptr, SEQ, N_H * D_HR, D_CQ);
  rope_q_kernel<<<(SEQ * N_H * 32 + 255) / 256, 256, 0, stream>>>(q_r);

  gemm_f32<<<dim3((N_H * D_H) / BN, SEQ / BM), 256, 0, stream>>>(c_kv, w_k, k_c, nullptr, SEQ, N_H * D_H, D_CKV);
  gemm_f32<<<dim3(D_MODEL / BN, SEQ / BM), 256, 0, stream>>>(c_kv, w_v, vbuf, nullptr, SEQ, D_MODEL, D_CKV);

  attn_flash<<<dim3(SEQ / AQ, N_H), 256, 0, stream>>>(q_c, q_r, k_c, k_r, vbuf, ao);

  gemm_f32<<<dim3(D_MODEL / BN, SEQ / BM), 256, 0, stream>>>(ao, w_o, out, x, SEQ, D_MODEL, D_MODEL);
}

// Round 4
// 1262.192 us; speedup vs baseline: 5.9814x; 2.9212x over previous
//
#include <hip/hip_runtime.h>
#include <hip/hip_bf16.h>
#include <math.h>

// Problem constants
#define D_MODEL 2048
#define N_H     16
#define D_H     128
#define D_CQ    768
#define D_CKV   512
#define D_HR    64
#define SEQ     2048

typedef short bf16x8 __attribute__((ext_vector_type(8)));
typedef float f32x4  __attribute__((ext_vector_type(4)));

__device__ inline short f2bf(float f) {
  union { float f; unsigned u; } v; v.f = f;
  unsigned r = (v.u + 0x7fff + ((v.u >> 16) & 1)) >> 16;
  return (short)r;
}

// ---------------------------------------------------------------------------
// RMSNorm
// ---------------------------------------------------------------------------
__global__ __launch_bounds__(256) void rmsnorm_kernel(
    const float* __restrict__ x, const float* __restrict__ w, float* __restrict__ h) {
  int row = blockIdx.x;
  int tid = threadIdx.x;
  const float* xr = x + (size_t)row * D_MODEL;
  float ss = 0.f;
  for (int i = tid; i < D_MODEL; i += 256) { float v = xr[i]; ss += v * v; }
  __shared__ float red[256];
  red[tid] = ss;
  __syncthreads();
  for (int s = 128; s > 0; s >>= 1) {
    if (tid < s) red[tid] += red[tid + s];
    __syncthreads();
  }
  float scale = rsqrtf(red[0] / (float)D_MODEL + 1.1920929e-7f);
  float* hr = h + (size_t)row * D_MODEL;
  for (int i = tid; i < D_MODEL; i += 256) hr[i] = xr[i] * scale * w[i];
}

// ---------------------------------------------------------------------------
// Tiled f32 GEMM (unchanged this round)
// ---------------------------------------------------------------------------
#define BM 64
#define BN 64
#define BK 16

__global__ __launch_bounds__(256) void gemm_f32(
    const float* __restrict__ A, const float* __restrict__ B,
    float* __restrict__ C, const float* __restrict__ addv,
    int M, int N, int K) {
  __shared__ float As[BK][BM + 4];
  __shared__ float Bs[BK][BN + 4];
  int tid = threadIdx.x;
  int bm = blockIdx.y * BM, bn = blockIdx.x * BN;
  int tm = (tid >> 4) << 2;
  int tn = (tid & 15) << 2;
  float acc[4][4] = {};

  for (int k0 = 0; k0 < K; k0 += BK) {
#pragma unroll
    for (int i = 0; i < 4; i++) {
      int idx = tid + i * 256;
      int r = idx >> 4, c = idx & 15;
      As[c][r] = A[(size_t)(bm + r) * K + k0 + c];
    }
#pragma unroll
    for (int i = 0; i < 4; i++) {
      int idx = tid + i * 256;
      int r = idx >> 6, c = idx & 63;
      Bs[r][c] = B[(size_t)(k0 + r) * N + bn + c];
    }
    __syncthreads();
#pragma unroll
    for (int kk = 0; kk < BK; kk++) {
      float4 a4 = *(const float4*)&As[kk][tm];
      float4 b4 = *(const float4*)&Bs[kk][tn];
      float av[4] = {a4.x, a4.y, a4.z, a4.w};
      float bv[4] = {b4.x, b4.y, b4.z, b4.w};
#pragma unroll
      for (int i = 0; i < 4; i++)
#pragma unroll
        for (int j = 0; j < 4; j++) acc[i][j] += av[i] * bv[j];
    }
    __syncthreads();
  }

#pragma unroll
  for (int i = 0; i < 4; i++) {
    size_t row = bm + tm + i;
    size_t off = row * N + bn + tn;
    float4 vout = make_float4(acc[i][0], acc[i][1], acc[i][2], acc[i][3]);
    if (addv) {
      float4 a4 = *(const float4*)&addv[off];
      vout.x += a4.x; vout.y += a4.y; vout.z += a4.z; vout.w += a4.w;
    }
    *(float4*)&C[off] = vout;
  }
}

// ---------------------------------------------------------------------------
// RoPE (interleaved pairs), in-place.
// ---------------------------------------------------------------------------
__global__ void rope_q_kernel(float* __restrict__ qr) {
  int idx = blockIdx.x * blockDim.x + threadIdx.x;
  if (idx >= SEQ * N_H * 32) return;
  int j = idx & 31;
  int rest = idx >> 5;
  int s = rest >> 4;
  float* p = qr + (size_t)rest * 64 + 2 * j;
  float inv = expf(-((float)(2 * j) / 64.0f) * logf(10000.0f));
  float ang = (float)s * inv;
  float c = cosf(ang), sn = sinf(ang);
  float x0 = p[0], x1 = p[1];
  p[0] = x0 * c - x1 * sn;
  p[1] = x0 * sn + x1 * c;
}

__global__ void rope_k_kernel(float* __restrict__ kr) {
  int idx = blockIdx.x * blockDim.x + threadIdx.x;
  if (idx >= SEQ * 32) return;
  int j = idx & 31;
  int s = idx >> 5;
  float* p = kr + (size_t)s * 64 + 2 * j;
  float inv = expf(-((float)(2 * j) / 64.0f) * logf(10000.0f));
  float ang = (float)s * inv;
  float c = cosf(ang), sn = sinf(ang);
  float x0 = p[0], x1 = p[1];
  p[0] = x0 * c - x1 * sn;
  p[1] = x0 * sn + x1 * c;
}

// ---------------------------------------------------------------------------
// cast_v_t: vbuf f32 (s, h*128+d) -> vt bf16 [h][d][s] (per-head transposed)
// LDS tile transpose so both global read and write are coalesced.
// ---------------------------------------------------------------------------
__global__ __launch_bounds__(256) void cast_v_t(
    const float* __restrict__ vbuf, short* __restrict__ vt) {
  int s0 = blockIdx.x * 64;
  int h = blockIdx.y;
  __shared__ short T[128][72];
  int tid = threadIdx.x;
#pragma unroll
  for (int it = 0; it < 32; it++) {
    int c = it * 256 + tid;           // 64 s-rows x 128 dims
    int r = c >> 7, d = c & 127;
    T[d][r] = f2bf(vbuf[(size_t)(s0 + r) * D_MODEL + h * 128 + d]);
  }
  __syncthreads();
#pragma unroll
  for (int it = 0; it < 32; it++) {
    int c = it * 256 + tid;           // 128 dims x 64 s
    int d = c >> 6, s = c & 63;
    vt[(size_t)(h * 128 + d) * SEQ + s0 + s] = T[d][s];
  }
}

// ---------------------------------------------------------------------------
// MFMA bf16 flash attention. Block = (head, 64-query tile), 4 waves.
// Wave owns 16 query rows. mfma_f32_16x16x32_bf16 for QK^T and PV.
// A-layout: A[m=lane&15][k=quad*8+j]; B-layout: B[k=quad*8+j][n=lane&15];
// C/D: col=lane&15, row=quad*4+reg.
// ---------------------------------------------------------------------------
#define TQ 64
#define TK 64

__global__ __launch_bounds__(256) void attn_mfma(
    const float* __restrict__ qc, const float* __restrict__ qr,
    const float* __restrict__ kc, const float* __restrict__ kr,
    const short* __restrict__ vt, float* __restrict__ out) {
  int h = blockIdx.y;
  int q0 = ((int)gridDim.x - 1 - (int)blockIdx.x) * TQ;  // heavy tiles first
  int tid = threadIdx.x;
  int wave = tid >> 6, lane = tid & 63;
  int lq = lane >> 4, l16 = lane & 15;

  __shared__ short Ks[TK][200];   // [key][192 dims], stride 400B (16B-aligned)
  __shared__ short Vt[128][72];   // [dim][64 keys], stride 144B
  __shared__ short Ps[TQ][72];    // [query][64 keys] — wave-private rows

  // ---- Q fragments to registers (once per block): 6 K-steps of 32 dims ----
  bf16x8 qf[6];
  int qrow = q0 + wave * 16 + l16;
  {
    const float* qcp = qc + (size_t)qrow * (N_H * D_H) + h * D_H;
    const float* qrp = qr + (size_t)qrow * (N_H * D_HR) + h * D_HR;
#pragma unroll
    for (int ks = 0; ks < 6; ks++) {
      int d = ks * 32 + lq * 8;
      const float* src = (d < 128) ? (qcp + d) : (qrp + (d - 128));
      float4 a = *(const float4*)src;
      float4 b = *(const float4*)(src + 4);
      qf[ks][0] = f2bf(a.x); qf[ks][1] = f2bf(a.y);
      qf[ks][2] = f2bf(a.z); qf[ks][3] = f2bf(a.w);
      qf[ks][4] = f2bf(b.x); qf[ks][5] = f2bf(b.y);
      qf[ks][6] = f2bf(b.z); qf[ks][7] = f2bf(b.w);
    }
  }

  f32x4 O[8];
#pragma unroll
  for (int i = 0; i < 8; i++) O[i] = (f32x4)0.f;
  float m_run[4] = {-1e30f, -1e30f, -1e30f, -1e30f};
  float l_run[4] = {0.f, 0.f, 0.f, 0.f};
  const float scale = 0.07216878364870323f;  // 1/sqrt(192)

  int nk = q0 / TK + 1;
  for (int t = 0; t < nk; t++) {
    int k0 = t * TK;
    // ---- stage K tile f32->bf16: 64 rows x 48 float4 chunks ----
#pragma unroll
    for (int it = 0; it < 12; it++) {
      int c = it * 256 + tid;
      int row = c / 48, q = c % 48;
      const float* src = (q < 32)
          ? kc + (size_t)(k0 + row) * (N_H * D_H) + h * D_H + q * 4
          : kr + (size_t)(k0 + row) * D_HR + (q - 32) * 4;
      float4 f = *(const float4*)src;
      short* dst = &Ks[row][q * 4];
      dst[0] = f2bf(f.x); dst[1] = f2bf(f.y);
      dst[2] = f2bf(f.z); dst[3] = f2bf(f.w);
    }
    // ---- stage V^T tile (bf16 copy, coalesced): 128 dims x 8 chunks ----
#pragma unroll
    for (int it = 0; it < 4; it++) {
      int c = it * 256 + tid;
      int d = c >> 3, c8 = c & 7;
      *(uint4*)&Vt[d][c8 * 8] =
          *(const uint4*)&vt[(size_t)(h * 128 + d) * SEQ + k0 + c8 * 8];
    }
    __syncthreads();

    // ---- S = Q K^T : 6 K-steps x 4 key-tiles ----
    f32x4 S[4];
#pragma unroll
    for (int nt = 0; nt < 4; nt++) S[nt] = (f32x4)0.f;
#pragma unroll
    for (int ks = 0; ks < 6; ks++) {
#pragma unroll
      for (int nt = 0; nt < 4; nt++) {
        bf16x8 b = *(const bf16x8*)&Ks[nt * 16 + l16][ks * 32 + lq * 8];
        S[nt] = __builtin_amdgcn_mfma_f32_16x16x32_bf16(qf[ks], b, S[nt], 0, 0, 0);
      }
    }

    // ---- online softmax (per row, in-wave over 16 lanes) ----
    bool diag = (k0 == q0);
#pragma unroll
    for (int i = 0; i < 4; i++) {
      int row = q0 + wave * 16 + lq * 4 + i;
      float sv[4];
      float mm = m_run[i];
#pragma unroll
      for (int nt = 0; nt < 4; nt++) {
        float s = S[nt][i] * scale;
        if (diag && (k0 + nt * 16 + l16 > row)) s = -1e30f;
        sv[nt] = s;
        mm = fmaxf(mm, s);
      }
#pragma unroll
      for (int off = 1; off < 16; off <<= 1)
        mm = fmaxf(mm, __shfl_xor(mm, off));
      float alpha = __expf(m_run[i] - mm);
      m_run[i] = mm;
      float ps = 0.f;
      short* prow = &Ps[wave * 16 + lq * 4 + i][l16];
#pragma unroll
      for (int nt = 0; nt < 4; nt++) {
        float p = __expf(sv[nt] - mm);
        ps += p;
        prow[nt * 16] = f2bf(p);
      }
#pragma unroll
      for (int off = 1; off < 16; off <<= 1)
        ps += __shfl_xor(ps, off);
      l_run[i] = l_run[i] * alpha + ps;
#pragma unroll
      for (int nt = 0; nt < 8; nt++) O[nt][i] *= alpha;
    }

    // ---- O += P V : 2 K-steps x 8 dim-tiles (Ps rows are wave-private) ----
#pragma unroll
    for (int kh = 0; kh < 2; kh++) {
      bf16x8 a = *(const bf16x8*)&Ps[wave * 16 + l16][kh * 32 + lq * 8];
#pragma unroll
      for (int nt = 0; nt < 8; nt++) {
        bf16x8 b = *(const bf16x8*)&Vt[nt * 16 + l16][kh * 32 + lq * 8];
        O[nt] = __builtin_amdgcn_mfma_f32_16x16x32_bf16(a, b, O[nt], 0, 0, 0);
      }
    }
    __syncthreads();
  }

  // ---- epilogue: out (s, h*128+d) f32 ----
#pragma unroll
  for (int i = 0; i < 4; i++) {
    int row = q0 + wave * 16 + lq * 4 + i;
    float inv = 1.0f / l_run[i];
#pragma unroll
    for (int nt = 0; nt < 8; nt++)
      out[(size_t)row * (N_H * D_H) + h * D_H + nt * 16 + l16] = O[nt][i] * inv;
  }
}

// ---------------------------------------------------------------------------
extern "C" void kernel_launch(void* const* d_in, const int* in_sizes, int n_in,
                              void* d_out, int out_size, void* d_ws, size_t ws_size,
                              hipStream_t stream) {
  const float* x      = (const float*)d_in[0];
  // d_in[1] = mask: causal triu, handled structurally — not read.
  const float* w_norm = (const float*)d_in[2];
  const float* w_cq   = (const float*)d_in[3];
  const float* w_q    = (const float*)d_in[4];
  const float* w_qr   = (const float*)d_in[5];
  const float* w_ckv  = (const float*)d_in[6];
  const float* w_k    = (const float*)d_in[7];
  const float* w_kr   = (const float*)d_in[8];
  const float* w_v    = (const float*)d_in[9];
  const float* w_o    = (const float*)d_in[10];
  float* out = (float*)d_out;

  float* ws = (float*)d_ws;
  float* h    = ws;                                // 2048*2048
  float* c_q  = h    + (size_t)SEQ * D_MODEL;      // 2048*768
  float* c_kv = c_q  + (size_t)SEQ * D_CQ;         // 2048*512
  float* k_r  = c_kv + (size_t)SEQ * D_CKV;        // 2048*64
  float* q_c  = k_r  + (size_t)SEQ * D_HR;         // 2048*2048
  float* q_r  = q_c  + (size_t)SEQ * (N_H * D_H);  // 2048*1024
  float* k_c  = q_r  + (size_t)SEQ * (N_H * D_HR); // 2048*2048
  float* vbuf = k_c  + (size_t)SEQ * (N_H * D_H);  // 2048*2048
  float* ao   = vbuf + (size_t)SEQ * (N_H * D_H);  // 2048*2048
  short* vt   = (short*)(ao + (size_t)SEQ * D_MODEL);  // bf16 [h][d][s], 8 MB

  rmsnorm_kernel<<<SEQ, 256, 0, stream>>>(x, w_norm, h);

  gemm_f32<<<dim3(D_CQ / BN, SEQ / BM), 256, 0, stream>>>(h, w_cq, c_q, nullptr, SEQ, D_CQ, D_MODEL);
  gemm_f32<<<dim3(D_CKV / BN, SEQ / BM), 256, 0, stream>>>(h, w_ckv, c_kv, nullptr, SEQ, D_CKV, D_MODEL);
  gemm_f32<<<dim3(D_HR / BN, SEQ / BM), 256, 0, stream>>>(h, w_kr, k_r, nullptr, SEQ, D_HR, D_MODEL);
  rope_k_kernel<<<(SEQ * 32 + 255) / 256, 256, 0, stream>>>(k_r);

  gemm_f32<<<dim3((N_H * D_H) / BN, SEQ / BM), 256, 0, stream>>>(c_q, w_q, q_c, nullptr, SEQ, N_H * D_H, D_CQ);
  gemm_f32<<<dim3((N_H * D_HR) / BN, SEQ / BM), 256, 0, stream>>>(c_q, w_qr, q_r, nullptr, SEQ, N_H * D_HR, D_CQ);
  rope_q_kernel<<<(SEQ * N_H * 32 + 255) / 256, 256, 0, stream>>>(q_r);

  gemm_f32<<<dim3((N_H * D_H) / BN, SEQ / BM), 256, 0, stream>>>(c_kv, w_k, k_c, nullptr, SEQ, N_H * D_H, D_CKV);
  gemm_f32<<<dim3(D_MODEL / BN, SEQ / BM), 256, 0, stream>>>(c_kv, w_v, vbuf, nullptr, SEQ, D_MODEL, D_CKV);

  cast_v_t<<<dim3(SEQ / 64, N_H), 256, 0, stream>>>(vbuf, vt);

  attn_mfma<<<dim3(SEQ / TQ, N_H), 256, 0, stream>>>(q_c, q_r, k_c, k_r, vt, ao);

  gemm_f32<<<dim3(D_MODEL / BN, SEQ / BM), 256, 0, stream>>>(ao, w_o, out, x, SEQ, D_MODEL, D_MODEL);
}

// Round 5
// 730.500 us; speedup vs baseline: 10.3349x; 1.7278x over previous
//
#include <hip/hip_runtime.h>
#include <hip/hip_bf16.h>
#include <math.h>

// Problem constants
#define D_MODEL 2048
#define N_H     16
#define D_H     128
#define D_CQ    768
#define D_CKV   512
#define D_HR    64
#define SEQ     2048

typedef short bf16x8 __attribute__((ext_vector_type(8)));
typedef float f32x4  __attribute__((ext_vector_type(4)));

__device__ inline short f2bf(float f) {
  union { float f; unsigned u; } v; v.f = f;
  unsigned r = (v.u + 0x7fff + ((v.u >> 16) & 1)) >> 16;
  return (short)r;
}

// async global->LDS, 16B per lane; lds dest must be wave-uniform base
__device__ inline void gld_lds16(const void* g, void* l) {
#if __has_builtin(__builtin_amdgcn_global_load_lds)
  __builtin_amdgcn_global_load_lds(
      (const __attribute__((address_space(1))) unsigned int*)g,
      (__attribute__((address_space(3))) unsigned int*)l, 16, 0, 0);
#else
  // fallback: explicit lane copy matching the same layout
  int lane = threadIdx.x & 63;
  *((uint4*)l + lane) = *(const uint4*)g;
#endif
}

// ---------------------------------------------------------------------------
// RMSNorm -> h_f32 and h_bf16
// ---------------------------------------------------------------------------
__global__ __launch_bounds__(256) void rmsnorm_kernel(
    const float* __restrict__ x, const float* __restrict__ w,
    float* __restrict__ hf, short* __restrict__ hb) {
  int row = blockIdx.x;
  int tid = threadIdx.x;
  const float* xr = x + (size_t)row * D_MODEL;
  float ss = 0.f;
  for (int i = tid; i < D_MODEL; i += 256) { float v = xr[i]; ss += v * v; }
  __shared__ float red[256];
  red[tid] = ss;
  __syncthreads();
  for (int s = 128; s > 0; s >>= 1) {
    if (tid < s) red[tid] += red[tid + s];
    __syncthreads();
  }
  float scale = rsqrtf(red[0] / (float)D_MODEL + 1.1920929e-7f);
  float* hr = hf + (size_t)row * D_MODEL;
  short* hbr = hb + (size_t)row * D_MODEL;
  for (int i = tid; i < D_MODEL; i += 256) {
    float v = xr[i] * scale * w[i];
    hr[i] = v;
    hbr[i] = f2bf(v);
  }
}

// ---------------------------------------------------------------------------
// Weight cast + transpose: W f32 [K][N] -> Wt bf16 [N][K]
// ---------------------------------------------------------------------------
__global__ __launch_bounds__(256) void cast_wt(
    const float* __restrict__ W, short* __restrict__ Wt, int K, int N) {
  int n0 = blockIdx.x * 64, k0 = blockIdx.y * 64;
  __shared__ short T[64][68];
  int tid = threadIdx.x;
#pragma unroll
  for (int it = 0; it < 16; it++) {
    int idx = it * 256 + tid;
    int r = idx >> 6, c = idx & 63;     // r: k-row, c: n-col
    T[c][r] = f2bf(W[(size_t)(k0 + r) * N + n0 + c]);
  }
  __syncthreads();
#pragma unroll
  for (int it = 0; it < 16; it++) {
    int idx = it * 256 + tid;
    int r = idx >> 6, c = idx & 63;     // r: n-row, c: k-col
    Wt[(size_t)(n0 + r) * K + k0 + c] = T[r][c];
  }
}

// ---------------------------------------------------------------------------
// MFMA bf16 GEMM (m97 structure): C[M,N] = A[M,K] @ Bt[N,K]^T
// A bf16 row-major, Bt bf16 [N][K] (pre-transposed B).
// 128x128 tile, BK=64, 4 waves in 2x2, each 64x64 (16 mfma acc tiles).
// global_load_lds width=16 into unpadded lane-contiguous LDS.
// Output: Cf (f32, + optional addv) or Cb (bf16).
// ---------------------------------------------------------------------------
__global__ __launch_bounds__(256) void gemm_bf16(
    const short* __restrict__ A, const short* __restrict__ Bt,
    float* __restrict__ Cf, short* __restrict__ Cb,
    const float* __restrict__ addv, int M, int N, int K) {
  __shared__ short As[128 * 64];   // [row m][k 0..63], 128B rows
  __shared__ short Bs[128 * 64];   // [row n][k 0..63]
  int tid = threadIdx.x;
  int w = tid >> 6, l = tid & 63;
  int lq = l >> 4, l16 = l & 15;
  int bm = blockIdx.y * 128, bn = blockIdx.x * 128;
  int wr = w >> 1, wc = w & 1;
  int wm0 = wr * 64, wn0 = wc * 64;

  f32x4 acc[4][4];
#pragma unroll
  for (int i = 0; i < 4; i++)
#pragma unroll
    for (int j = 0; j < 4; j++) acc[i][j] = (f32x4)0.f;

  int rsub = (l >> 3);        // 0..7 row within 8-row group
  int csub = (l & 7) * 8;     // element offset within 64-elem row

  for (int k0 = 0; k0 < K; k0 += 64) {
    // stage A: 128 rows x 64 bf16; each wave-issue covers 8 rows (1KB)
#pragma unroll
    for (int i = 0; i < 4; i++) {
      int r0 = i * 32 + w * 8;
      gld_lds16(A + (size_t)(bm + r0 + rsub) * K + k0 + csub, As + r0 * 64);
    }
#pragma unroll
    for (int i = 0; i < 4; i++) {
      int r0 = i * 32 + w * 8;
      gld_lds16(Bt + (size_t)(bn + r0 + rsub) * K + k0 + csub, Bs + r0 * 64);
    }
    __syncthreads();

#pragma unroll
    for (int ks = 0; ks < 2; ks++) {
      bf16x8 af[4], bf[4];
#pragma unroll
      for (int mt = 0; mt < 4; mt++)
        af[mt] = *(const bf16x8*)&As[(wm0 + mt * 16 + l16) * 64 + ks * 32 + lq * 8];
#pragma unroll
      for (int nt = 0; nt < 4; nt++)
        bf[nt] = *(const bf16x8*)&Bs[(wn0 + nt * 16 + l16) * 64 + ks * 32 + lq * 8];
#pragma unroll
      for (int mt = 0; mt < 4; mt++)
#pragma unroll
        for (int nt = 0; nt < 4; nt++)
          acc[mt][nt] = __builtin_amdgcn_mfma_f32_16x16x32_bf16(af[mt], bf[nt], acc[mt][nt], 0, 0, 0);
    }
    __syncthreads();
  }

  // epilogue: C row = bm+wm0+mt*16+lq*4+i, col = bn+wn0+nt*16+l16
  if (Cb) {
#pragma unroll
    for (int mt = 0; mt < 4; mt++)
#pragma unroll
      for (int i = 0; i < 4; i++) {
        size_t row = bm + wm0 + mt * 16 + lq * 4 + i;
#pragma unroll
        for (int nt = 0; nt < 4; nt++)
          Cb[row * N + bn + wn0 + nt * 16 + l16] = f2bf(acc[mt][nt][i]);
      }
  } else {
#pragma unroll
    for (int mt = 0; mt < 4; mt++)
#pragma unroll
      for (int i = 0; i < 4; i++) {
        size_t row = bm + wm0 + mt * 16 + lq * 4 + i;
#pragma unroll
        for (int nt = 0; nt < 4; nt++) {
          size_t off = row * N + bn + wn0 + nt * 16 + l16;
          float v = acc[mt][nt][i];
          if (addv) v += addv[off];
          Cf[off] = v;
        }
      }
  }
}

// ---------------------------------------------------------------------------
// f32 GEMM (kept only for the tiny h @ w_kr, N=64)
// ---------------------------------------------------------------------------
#define BM 64
#define BN 64
#define BK 16

__global__ __launch_bounds__(256) void gemm_f32(
    const float* __restrict__ A, const float* __restrict__ B,
    float* __restrict__ C, const float* __restrict__ addv,
    int M, int N, int K) {
  __shared__ float Asf[BK][BM + 4];
  __shared__ float Bsf[BK][BN + 4];
  int tid = threadIdx.x;
  int bm = blockIdx.y * BM, bn = blockIdx.x * BN;
  int tm = (tid >> 4) << 2;
  int tn = (tid & 15) << 2;
  float acc[4][4] = {};

  for (int k0 = 0; k0 < K; k0 += BK) {
#pragma unroll
    for (int i = 0; i < 4; i++) {
      int idx = tid + i * 256;
      int r = idx >> 4, c = idx & 15;
      Asf[c][r] = A[(size_t)(bm + r) * K + k0 + c];
    }
#pragma unroll
    for (int i = 0; i < 4; i++) {
      int idx = tid + i * 256;
      int r = idx >> 6, c = idx & 63;
      Bsf[r][c] = B[(size_t)(k0 + r) * N + bn + c];
    }
    __syncthreads();
#pragma unroll
    for (int kk = 0; kk < BK; kk++) {
      float4 a4 = *(const float4*)&Asf[kk][tm];
      float4 b4 = *(const float4*)&Bsf[kk][tn];
      float av[4] = {a4.x, a4.y, a4.z, a4.w};
      float bv[4] = {b4.x, b4.y, b4.z, b4.w};
#pragma unroll
      for (int i = 0; i < 4; i++)
#pragma unroll
        for (int j = 0; j < 4; j++) acc[i][j] += av[i] * bv[j];
    }
    __syncthreads();
  }

#pragma unroll
  for (int i = 0; i < 4; i++) {
    size_t row = bm + tm + i;
    size_t off = row * N + bn + tn;
    float4 vout = make_float4(acc[i][0], acc[i][1], acc[i][2], acc[i][3]);
    if (addv) {
      float4 a4 = *(const float4*)&addv[off];
      vout.x += a4.x; vout.y += a4.y; vout.z += a4.z; vout.w += a4.w;
    }
    *(float4*)&C[off] = vout;
  }
}

// ---------------------------------------------------------------------------
// RoPE (interleaved pairs), in-place.
// ---------------------------------------------------------------------------
__global__ void rope_q_kernel(float* __restrict__ qr) {
  int idx = blockIdx.x * blockDim.x + threadIdx.x;
  if (idx >= SEQ * N_H * 32) return;
  int j = idx & 31;
  int rest = idx >> 5;
  int s = rest >> 4;
  float* p = qr + (size_t)rest * 64 + 2 * j;
  float inv = expf(-((float)(2 * j) / 64.0f) * logf(10000.0f));
  float ang = (float)s * inv;
  float c = cosf(ang), sn = sinf(ang);
  float x0 = p[0], x1 = p[1];
  p[0] = x0 * c - x1 * sn;
  p[1] = x0 * sn + x1 * c;
}

__global__ void rope_k_kernel(float* __restrict__ kr) {
  int idx = blockIdx.x * blockDim.x + threadIdx.x;
  if (idx >= SEQ * 32) return;
  int j = idx & 31;
  int s = idx >> 5;
  float* p = kr + (size_t)s * 64 + 2 * j;
  float inv = expf(-((float)(2 * j) / 64.0f) * logf(10000.0f));
  float ang = (float)s * inv;
  float c = cosf(ang), sn = sinf(ang);
  float x0 = p[0], x1 = p[1];
  p[0] = x0 * c - x1 * sn;
  p[1] = x0 * sn + x1 * c;
}

// ---------------------------------------------------------------------------
// cast_v_t: vbuf f32 (s, h*128+d) -> vt bf16 [h][d][s]
// ---------------------------------------------------------------------------
__global__ __launch_bounds__(256) void cast_v_t(
    const float* __restrict__ vbuf, short* __restrict__ vt) {
  int s0 = blockIdx.x * 64;
  int h = blockIdx.y;
  __shared__ short T[128][72];
  int tid = threadIdx.x;
#pragma unroll
  for (int it = 0; it < 32; it++) {
    int c = it * 256 + tid;
    int r = c >> 7, d = c & 127;
    T[d][r] = f2bf(vbuf[(size_t)(s0 + r) * D_MODEL + h * 128 + d]);
  }
  __syncthreads();
#pragma unroll
  for (int it = 0; it < 32; it++) {
    int c = it * 256 + tid;
    int d = c >> 6, s = c & 63;
    vt[(size_t)(h * 128 + d) * SEQ + s0 + s] = T[d][s];
  }
}

// ---------------------------------------------------------------------------
// MFMA bf16 flash attention (round-4 verified), epilogue now writes bf16 ao.
// ---------------------------------------------------------------------------
#define TQ 64
#define TK 64

__global__ __launch_bounds__(256) void attn_mfma(
    const float* __restrict__ qc, const float* __restrict__ qr,
    const float* __restrict__ kc, const float* __restrict__ kr,
    const short* __restrict__ vt, short* __restrict__ aob) {
  int h = blockIdx.y;
  int q0 = ((int)gridDim.x - 1 - (int)blockIdx.x) * TQ;
  int tid = threadIdx.x;
  int wave = tid >> 6, lane = tid & 63;
  int lq = lane >> 4, l16 = lane & 15;

  __shared__ short Ks[TK][200];
  __shared__ short Vt[128][72];
  __shared__ short Ps[TQ][72];

  bf16x8 qf[6];
  int qrow = q0 + wave * 16 + l16;
  {
    const float* qcp = qc + (size_t)qrow * (N_H * D_H) + h * D_H;
    const float* qrp = qr + (size_t)qrow * (N_H * D_HR) + h * D_HR;
#pragma unroll
    for (int ks = 0; ks < 6; ks++) {
      int d = ks * 32 + lq * 8;
      const float* src = (d < 128) ? (qcp + d) : (qrp + (d - 128));
      float4 a = *(const float4*)src;
      float4 b = *(const float4*)(src + 4);
      qf[ks][0] = f2bf(a.x); qf[ks][1] = f2bf(a.y);
      qf[ks][2] = f2bf(a.z); qf[ks][3] = f2bf(a.w);
      qf[ks][4] = f2bf(b.x); qf[ks][5] = f2bf(b.y);
      qf[ks][6] = f2bf(b.z); qf[ks][7] = f2bf(b.w);
    }
  }

  f32x4 O[8];
#pragma unroll
  for (int i = 0; i < 8; i++) O[i] = (f32x4)0.f;
  float m_run[4] = {-1e30f, -1e30f, -1e30f, -1e30f};
  float l_run[4] = {0.f, 0.f, 0.f, 0.f};
  const float scale = 0.07216878364870323f;  // 1/sqrt(192)

  int nk = q0 / TK + 1;
  for (int t = 0; t < nk; t++) {
    int k0 = t * TK;
#pragma unroll
    for (int it = 0; it < 12; it++) {
      int c = it * 256 + tid;
      int row = c / 48, q = c % 48;
      const float* src = (q < 32)
          ? kc + (size_t)(k0 + row) * (N_H * D_H) + h * D_H + q * 4
          : kr + (size_t)(k0 + row) * D_HR + (q - 32) * 4;
      float4 f = *(const float4*)src;
      short* dst = &Ks[row][q * 4];
      dst[0] = f2bf(f.x); dst[1] = f2bf(f.y);
      dst[2] = f2bf(f.z); dst[3] = f2bf(f.w);
    }
#pragma unroll
    for (int it = 0; it < 4; it++) {
      int c = it * 256 + tid;
      int d = c >> 3, c8 = c & 7;
      *(uint4*)&Vt[d][c8 * 8] =
          *(const uint4*)&vt[(size_t)(h * 128 + d) * SEQ + k0 + c8 * 8];
    }
    __syncthreads();

    f32x4 S[4];
#pragma unroll
    for (int nt = 0; nt < 4; nt++) S[nt] = (f32x4)0.f;
#pragma unroll
    for (int ks = 0; ks < 6; ks++) {
#pragma unroll
      for (int nt = 0; nt < 4; nt++) {
        bf16x8 b = *(const bf16x8*)&Ks[nt * 16 + l16][ks * 32 + lq * 8];
        S[nt] = __builtin_amdgcn_mfma_f32_16x16x32_bf16(qf[ks], b, S[nt], 0, 0, 0);
      }
    }

    bool diag = (k0 == q0);
#pragma unroll
    for (int i = 0; i < 4; i++) {
      int row = q0 + wave * 16 + lq * 4 + i;
      float sv[4];
      float mm = m_run[i];
#pragma unroll
      for (int nt = 0; nt < 4; nt++) {
        float s = S[nt][i] * scale;
        if (diag && (k0 + nt * 16 + l16 > row)) s = -1e30f;
        sv[nt] = s;
        mm = fmaxf(mm, s);
      }
#pragma unroll
      for (int off = 1; off < 16; off <<= 1)
        mm = fmaxf(mm, __shfl_xor(mm, off));
      float alpha = __expf(m_run[i] - mm);
      m_run[i] = mm;
      float ps = 0.f;
      short* prow = &Ps[wave * 16 + lq * 4 + i][l16];
#pragma unroll
      for (int nt = 0; nt < 4; nt++) {
        float p = __expf(sv[nt] - mm);
        ps += p;
        prow[nt * 16] = f2bf(p);
      }
#pragma unroll
      for (int off = 1; off < 16; off <<= 1)
        ps += __shfl_xor(ps, off);
      l_run[i] = l_run[i] * alpha + ps;
#pragma unroll
      for (int nt = 0; nt < 8; nt++) O[nt][i] *= alpha;
    }

#pragma unroll
    for (int kh = 0; kh < 2; kh++) {
      bf16x8 a = *(const bf16x8*)&Ps[wave * 16 + l16][kh * 32 + lq * 8];
#pragma unroll
      for (int nt = 0; nt < 8; nt++) {
        bf16x8 b = *(const bf16x8*)&Vt[nt * 16 + l16][kh * 32 + lq * 8];
        O[nt] = __builtin_amdgcn_mfma_f32_16x16x32_bf16(a, b, O[nt], 0, 0, 0);
      }
    }
    __syncthreads();
  }

#pragma unroll
  for (int i = 0; i < 4; i++) {
    int row = q0 + wave * 16 + lq * 4 + i;
    float inv = 1.0f / l_run[i];
#pragma unroll
    for (int nt = 0; nt < 8; nt++)
      aob[(size_t)row * (N_H * D_H) + h * D_H + nt * 16 + l16] = f2bf(O[nt][i] * inv);
  }
}

// ---------------------------------------------------------------------------
extern "C" void kernel_launch(void* const* d_in, const int* in_sizes, int n_in,
                              void* d_out, int out_size, void* d_ws, size_t ws_size,
                              hipStream_t stream) {
  const float* x      = (const float*)d_in[0];
  // d_in[1] = mask: causal triu, handled structurally — not read.
  const float* w_norm = (const float*)d_in[2];
  const float* w_cq   = (const float*)d_in[3];
  const float* w_q    = (const float*)d_in[4];
  const float* w_qr   = (const float*)d_in[5];
  const float* w_ckv  = (const float*)d_in[6];
  const float* w_k    = (const float*)d_in[7];
  const float* w_kr   = (const float*)d_in[8];
  const float* w_v    = (const float*)d_in[9];
  const float* w_o    = (const float*)d_in[10];
  float* out = (float*)d_out;

  char* ws = (char*)d_ws;
  float* h_f32 = (float*)ws;                       ws += (size_t)SEQ * D_MODEL * 4;
  float* k_r   = (float*)ws;                       ws += (size_t)SEQ * D_HR * 4;
  float* q_c   = (float*)ws;                       ws += (size_t)SEQ * N_H * D_H * 4;
  float* q_r   = (float*)ws;                       ws += (size_t)SEQ * N_H * D_HR * 4;
  float* k_c   = (float*)ws;                       ws += (size_t)SEQ * N_H * D_H * 4;
  float* vbuf  = (float*)ws;                       ws += (size_t)SEQ * D_MODEL * 4;
  short* h_bf  = (short*)ws;                       ws += (size_t)SEQ * D_MODEL * 2;
  short* cq_bf = (short*)ws;                       ws += (size_t)SEQ * D_CQ * 2;
  short* ckv_bf= (short*)ws;                       ws += (size_t)SEQ * D_CKV * 2;
  short* vt    = (short*)ws;                       ws += (size_t)SEQ * D_MODEL * 2;
  short* ao_bf = (short*)ws;                       ws += (size_t)SEQ * D_MODEL * 2;
  short* wt_cq = (short*)ws;                       ws += (size_t)D_MODEL * D_CQ * 2;
  short* wt_q  = (short*)ws;                       ws += (size_t)D_CQ * N_H * D_H * 2;
  short* wt_qr = (short*)ws;                       ws += (size_t)D_CQ * N_H * D_HR * 2;
  short* wt_ckv= (short*)ws;                       ws += (size_t)D_MODEL * D_CKV * 2;
  short* wt_k  = (short*)ws;                       ws += (size_t)D_CKV * N_H * D_H * 2;
  short* wt_v  = (short*)ws;                       ws += (size_t)D_CKV * D_MODEL * 2;
  short* wt_o  = (short*)ws;                       ws += (size_t)N_H * D_H * D_MODEL * 2;

  // weight casts (independent of activations)
  cast_wt<<<dim3(D_CQ / 64, D_MODEL / 64), 256, 0, stream>>>(w_cq, wt_cq, D_MODEL, D_CQ);
  cast_wt<<<dim3((N_H * D_H) / 64, D_CQ / 64), 256, 0, stream>>>(w_q, wt_q, D_CQ, N_H * D_H);
  cast_wt<<<dim3((N_H * D_HR) / 64, D_CQ / 64), 256, 0, stream>>>(w_qr, wt_qr, D_CQ, N_H * D_HR);
  cast_wt<<<dim3(D_CKV / 64, D_MODEL / 64), 256, 0, stream>>>(w_ckv, wt_ckv, D_MODEL, D_CKV);
  cast_wt<<<dim3((N_H * D_H) / 64, D_CKV / 64), 256, 0, stream>>>(w_k, wt_k, D_CKV, N_H * D_H);
  cast_wt<<<dim3(D_MODEL / 64, D_CKV / 64), 256, 0, stream>>>(w_v, wt_v, D_CKV, D_MODEL);
  cast_wt<<<dim3(D_MODEL / 64, (N_H * D_H) / 64), 256, 0, stream>>>(w_o, wt_o, N_H * D_H, D_MODEL);

  rmsnorm_kernel<<<SEQ, 256, 0, stream>>>(x, w_norm, h_f32, h_bf);

  // c_q = h @ w_cq (bf16 out), c_kv = h @ w_ckv (bf16 out)
  gemm_bf16<<<dim3(D_CQ / 128, SEQ / 128), 256, 0, stream>>>(
      h_bf, wt_cq, nullptr, cq_bf, nullptr, SEQ, D_CQ, D_MODEL);
  gemm_bf16<<<dim3(D_CKV / 128, SEQ / 128), 256, 0, stream>>>(
      h_bf, wt_ckv, nullptr, ckv_bf, nullptr, SEQ, D_CKV, D_MODEL);

  // k_r = rope(h @ w_kr)  (N=64, keep f32 path)
  gemm_f32<<<dim3(D_HR / BN, SEQ / BM), 256, 0, stream>>>(h_f32, w_kr, k_r, nullptr, SEQ, D_HR, D_MODEL);
  rope_k_kernel<<<(SEQ * 32 + 255) / 256, 256, 0, stream>>>(k_r);

  // q_c, q_r from c_q
  gemm_bf16<<<dim3((N_H * D_H) / 128, SEQ / 128), 256, 0, stream>>>(
      cq_bf, wt_q, q_c, nullptr, nullptr, SEQ, N_H * D_H, D_CQ);
  gemm_bf16<<<dim3((N_H * D_HR) / 128, SEQ / 128), 256, 0, stream>>>(
      cq_bf, wt_qr, q_r, nullptr, nullptr, SEQ, N_H * D_HR, D_CQ);
  rope_q_kernel<<<(SEQ * N_H * 32 + 255) / 256, 256, 0, stream>>>(q_r);

  // k_c, v from c_kv
  gemm_bf16<<<dim3((N_H * D_H) / 128, SEQ / 128), 256, 0, stream>>>(
      ckv_bf, wt_k, k_c, nullptr, nullptr, SEQ, N_H * D_H, D_CKV);
  gemm_bf16<<<dim3(D_MODEL / 128, SEQ / 128), 256, 0, stream>>>(
      ckv_bf, wt_v, vbuf, nullptr, nullptr, SEQ, D_MODEL, D_CKV);

  cast_v_t<<<dim3(SEQ / 64, N_H), 256, 0, stream>>>(vbuf, vt);

  attn_mfma<<<dim3(SEQ / TQ, N_H), 256, 0, stream>>>(q_c, q_r, k_c, k_r, vt, ao_bf);

  // out = ao @ w_o + x
  gemm_bf16<<<dim3(D_MODEL / 128, SEQ / 128), 256, 0, stream>>>(
      ao_bf, wt_o, out, nullptr, x, SEQ, D_MODEL, D_MODEL);
}

// Round 7
// 639.886 us; speedup vs baseline: 11.7984x; 1.1416x over previous
//
#include <hip/hip_runtime.h>
#include <hip/hip_bf16.h>
#include <math.h>

// Problem constants
#define D_MODEL 2048
#define N_H     16
#define D_H     128
#define D_CQ    768
#define D_CKV   512
#define D_HR    64
#define SEQ     2048

typedef short bf16x8 __attribute__((ext_vector_type(8)));
typedef float f32x4  __attribute__((ext_vector_type(4)));

__device__ inline short f2bf(float f) {
  union { float f; unsigned u; } v; v.f = f;
  unsigned r = (v.u + 0x7fff + ((v.u >> 16) & 1)) >> 16;
  return (short)r;
}
__device__ inline float bf2f(short s) {
  union { float f; unsigned u; } v; v.u = ((unsigned)(unsigned short)s) << 16;
  return v.f;
}

// async global->LDS, 16B per lane; lds dest must be wave-uniform base
__device__ inline void gld_lds16(const void* g, void* l) {
#if __has_builtin(__builtin_amdgcn_global_load_lds)
  __builtin_amdgcn_global_load_lds(
      (const __attribute__((address_space(1))) unsigned int*)g,
      (__attribute__((address_space(3))) unsigned int*)l, 16, 0, 0);
#else
  int lane = threadIdx.x & 63;
  *((uint4*)l + lane) = *(const uint4*)g;
#endif
}

// ---------------------------------------------------------------------------
// RMSNorm -> h_f32 and h_bf16
// ---------------------------------------------------------------------------
__global__ __launch_bounds__(256) void rmsnorm_kernel(
    const float* __restrict__ x, const float* __restrict__ w,
    float* __restrict__ hf, short* __restrict__ hb) {
  int row = blockIdx.x;
  int tid = threadIdx.x;
  const float* xr = x + (size_t)row * D_MODEL;
  float ss = 0.f;
  for (int i = tid; i < D_MODEL; i += 256) { float v = xr[i]; ss += v * v; }
  __shared__ float red[256];
  red[tid] = ss;
  __syncthreads();
  for (int s = 128; s > 0; s >>= 1) {
    if (tid < s) red[tid] += red[tid + s];
    __syncthreads();
  }
  float scale = rsqrtf(red[0] / (float)D_MODEL + 1.1920929e-7f);
  float* hr = hf + (size_t)row * D_MODEL;
  short* hbr = hb + (size_t)row * D_MODEL;
  for (int i = tid; i < D_MODEL; i += 256) {
    float v = xr[i] * scale * w[i];
    hr[i] = v;
    hbr[i] = f2bf(v);
  }
}

// ---------------------------------------------------------------------------
// Weight cast + transpose: W f32 [K][N] -> Wt bf16 [N][K]
// ---------------------------------------------------------------------------
__global__ __launch_bounds__(256) void cast_wt(
    const float* __restrict__ W, short* __restrict__ Wt, int K, int N) {
  int n0 = blockIdx.x * 64, k0 = blockIdx.y * 64;
  __shared__ short T[64][68];
  int tid = threadIdx.x;
#pragma unroll
  for (int it = 0; it < 16; it++) {
    int idx = it * 256 + tid;
    int r = idx >> 6, c = idx & 63;
    T[c][r] = f2bf(W[(size_t)(k0 + r) * N + n0 + c]);
  }
  __syncthreads();
#pragma unroll
  for (int it = 0; it < 16; it++) {
    int idx = it * 256 + tid;
    int r = idx >> 6, c = idx & 63;
    Wt[(size_t)(n0 + r) * K + k0 + c] = T[r][c];
  }
}

// ---------------------------------------------------------------------------
// MFMA bf16 GEMM: C[M,N] = A[M,K] @ Bt[N,K]^T
// mode 0: f32 out (+addv); mode 1: bf16 row-major; mode 2: bf16 packed
//         per-head [n>>7][row][192] layout (MLA q/k pack, first 128 dims).
// ---------------------------------------------------------------------------
__global__ __launch_bounds__(256) void gemm_bf16(
    const short* __restrict__ A, const short* __restrict__ Bt,
    float* __restrict__ Cf, short* __restrict__ Cb,
    const float* __restrict__ addv, int M, int N, int K, int mode) {
  __shared__ short As[128 * 64];
  __shared__ short Bs[128 * 64];
  int tid = threadIdx.x;
  int w = tid >> 6, l = tid & 63;
  int lq = l >> 4, l16 = l & 15;
  int bm = blockIdx.y * 128, bn = blockIdx.x * 128;
  int wr = w >> 1, wc = w & 1;
  int wm0 = wr * 64, wn0 = wc * 64;

  f32x4 acc[4][4];
#pragma unroll
  for (int i = 0; i < 4; i++)
#pragma unroll
    for (int j = 0; j < 4; j++) acc[i][j] = (f32x4)0.f;

  int rsub = (l >> 3);
  int csub = (l & 7) * 8;

  for (int k0 = 0; k0 < K; k0 += 64) {
#pragma unroll
    for (int i = 0; i < 4; i++) {
      int r0 = i * 32 + w * 8;
      gld_lds16(A + (size_t)(bm + r0 + rsub) * K + k0 + csub, As + r0 * 64);
    }
#pragma unroll
    for (int i = 0; i < 4; i++) {
      int r0 = i * 32 + w * 8;
      gld_lds16(Bt + (size_t)(bn + r0 + rsub) * K + k0 + csub, Bs + r0 * 64);
    }
    __syncthreads();

#pragma unroll
    for (int ks = 0; ks < 2; ks++) {
      bf16x8 af[4], bfr[4];
#pragma unroll
      for (int mt = 0; mt < 4; mt++)
        af[mt] = *(const bf16x8*)&As[(wm0 + mt * 16 + l16) * 64 + ks * 32 + lq * 8];
#pragma unroll
      for (int nt = 0; nt < 4; nt++)
        bfr[nt] = *(const bf16x8*)&Bs[(wn0 + nt * 16 + l16) * 64 + ks * 32 + lq * 8];
#pragma unroll
      for (int mt = 0; mt < 4; mt++)
#pragma unroll
        for (int nt = 0; nt < 4; nt++)
          acc[mt][nt] = __builtin_amdgcn_mfma_f32_16x16x32_bf16(af[mt], bfr[nt], acc[mt][nt], 0, 0, 0);
    }
    __syncthreads();
  }

#pragma unroll
  for (int mt = 0; mt < 4; mt++)
#pragma unroll
    for (int i = 0; i < 4; i++) {
      size_t row = bm + wm0 + mt * 16 + lq * 4 + i;
#pragma unroll
      for (int nt = 0; nt < 4; nt++) {
        int col = bn + wn0 + nt * 16 + l16;
        float v = acc[mt][nt][i];
        if (mode == 0) {
          size_t off = row * N + col;
          if (addv) v += addv[off];
          Cf[off] = v;
        } else if (mode == 1) {
          Cb[row * N + col] = f2bf(v);
        } else {
          Cb[((size_t)(col >> 7) * M + row) * 192 + (col & 127)] = f2bf(v);
        }
      }
    }
}

// ---------------------------------------------------------------------------
// f32 GEMM (kept only for the tiny h @ w_kr, N=64)
// ---------------------------------------------------------------------------
#define BM 64
#define BN 64
#define BK 16

__global__ __launch_bounds__(256) void gemm_f32(
    const float* __restrict__ A, const float* __restrict__ B,
    float* __restrict__ C, const float* __restrict__ addv,
    int M, int N, int K) {
  __shared__ float Asf[BK][BM + 4];
  __shared__ float Bsf[BK][BN + 4];
  int tid = threadIdx.x;
  int bm = blockIdx.y * BM, bn = blockIdx.x * BN;
  int tm = (tid >> 4) << 2;
  int tn = (tid & 15) << 2;
  float acc[4][4] = {};

  for (int k0 = 0; k0 < K; k0 += BK) {
#pragma unroll
    for (int i = 0; i < 4; i++) {
      int idx = tid + i * 256;
      int r = idx >> 4, c = idx & 15;
      Asf[c][r] = A[(size_t)(bm + r) * K + k0 + c];
    }
#pragma unroll
    for (int i = 0; i < 4; i++) {
      int idx = tid + i * 256;
      int r = idx >> 6, c = idx & 63;
      Bsf[r][c] = B[(size_t)(k0 + r) * N + bn + c];
    }
    __syncthreads();
#pragma unroll
    for (int kk = 0; kk < BK; kk++) {
      float4 a4 = *(const float4*)&Asf[kk][tm];
      float4 b4 = *(const float4*)&Bsf[kk][tn];
      float av[4] = {a4.x, a4.y, a4.z, a4.w};
      float bv[4] = {b4.x, b4.y, b4.z, b4.w};
#pragma unroll
      for (int i = 0; i < 4; i++)
#pragma unroll
        for (int j = 0; j < 4; j++) acc[i][j] += av[i] * bv[j];
    }
    __syncthreads();
  }

#pragma unroll
  for (int i = 0; i < 4; i++) {
    size_t row = bm + tm + i;
    size_t off = row * N + bn + tn;
    float4 vout = make_float4(acc[i][0], acc[i][1], acc[i][2], acc[i][3]);
    if (addv) {
      float4 a4 = *(const float4*)&addv[off];
      vout.x += a4.x; vout.y += a4.y; vout.z += a4.z; vout.w += a4.w;
    }
    *(float4*)&C[off] = vout;
  }
}

// ---------------------------------------------------------------------------
// RoPE: read f32 GEMM output, write rotated bf16 into packed qb/kb buffers.
// qb/kb layout: [h][s][192], rope dims at offset 128.
// ---------------------------------------------------------------------------
__global__ void rope_q_kernel(const float* __restrict__ qr, short* __restrict__ qb) {
  int idx = blockIdx.x * blockDim.x + threadIdx.x;
  if (idx >= SEQ * N_H * 32) return;
  int j = idx & 31;
  int hh = (idx >> 5) & 15;
  int s = idx >> 9;
  const float* p = qr + ((size_t)s * N_H + hh) * 64 + 2 * j;
  float inv = expf(-((float)(2 * j) / 64.0f) * logf(10000.0f));
  float ang = (float)s * inv;
  float c = cosf(ang), sn = sinf(ang);
  float x0 = p[0], x1 = p[1];
  short* q = qb + ((size_t)hh * SEQ + s) * 192 + 128 + 2 * j;
  q[0] = f2bf(x0 * c - x1 * sn);
  q[1] = f2bf(x0 * sn + x1 * c);
}

__global__ void rope_k_kernel(const float* __restrict__ kr, short* __restrict__ kb) {
  int idx = blockIdx.x * blockDim.x + threadIdx.x;
  if (idx >= SEQ * 32) return;
  int j = idx & 31;
  int s = idx >> 5;
  const float* p = kr + (size_t)s * 64 + 2 * j;
  float inv = expf(-((float)(2 * j) / 64.0f) * logf(10000.0f));
  float ang = (float)s * inv;
  float c = cosf(ang), sn = sinf(ang);
  float y0 = p[0] * c - p[1] * sn;
  float y1 = p[0] * sn + p[1] * c;
  short b0 = f2bf(y0), b1 = f2bf(y1);
#pragma unroll
  for (int hh = 0; hh < N_H; hh++) {
    short* k = kb + ((size_t)hh * SEQ + s) * 192 + 128 + 2 * j;
    k[0] = b0;
    k[1] = b1;
  }
}

// ---------------------------------------------------------------------------
// cast_v_t: vb bf16 (s, h*128+d) -> vt bf16 [h][d][s]
// ---------------------------------------------------------------------------
__global__ __launch_bounds__(256) void cast_v_t(
    const short* __restrict__ vb, short* __restrict__ vt) {
  int s0 = blockIdx.x * 64;
  int h = blockIdx.y;
  __shared__ short T[128][72];
  int tid = threadIdx.x;
#pragma unroll
  for (int it = 0; it < 32; it++) {
    int c = it * 256 + tid;
    int r = c >> 7, d = c & 127;
    T[d][r] = vb[(size_t)(s0 + r) * D_MODEL + h * 128 + d];
  }
  __syncthreads();
#pragma unroll
  for (int it = 0; it < 32; it++) {
    int c = it * 256 + tid;
    int d = c >> 6, s = c & 63;
    vt[(size_t)(h * 128 + d) * SEQ + s0 + s] = T[d][s];
  }
}

// ---------------------------------------------------------------------------
// MFMA bf16 flash attention, 2-way split-K. Block = (head, q-tile, split).
// split processes k-tiles t = split, split+2, ... Partial (O bf16, m, l f32)
// written to workspace; attn_merge combines.
// K staging: each Ks row = 192 shorts = 24 uint4 chunks; 64 rows = 1536
// chunks = 6 iters x 256 threads.  (Round-6 bug: 3 iters left dims 96..191
// uninitialized -> NaN.)
// ---------------------------------------------------------------------------
#define TQ 64
#define TK 64

__global__ __launch_bounds__(256) void attn_mfma(
    const short* __restrict__ qb, const short* __restrict__ kb,
    const short* __restrict__ vt, short* __restrict__ Opart,
    float* __restrict__ Mpart, float* __restrict__ Lpart) {
  int h = blockIdx.y;
  int bx = blockIdx.x;
  int qt = 31 - (bx >> 1);      // heavy tiles first (LPT)
  int split = bx & 1;
  int q0 = qt * TQ;
  int nk = qt + 1;
  int tid = threadIdx.x;
  int wave = tid >> 6, lane = tid & 63;
  int lq = lane >> 4, l16 = lane & 15;

  __shared__ short Ks[TK][200];   // [key][192 dims]
  __shared__ short Vs[128][72];   // [dim][64 keys]
  __shared__ short Ps[TQ][72];    // [query][64 keys] — wave-private rows

  // ---- Q fragments (bf16 direct) ----
  bf16x8 qf[6];
  {
    const short* qp = qb + ((size_t)h * SEQ + q0 + wave * 16 + l16) * 192;
#pragma unroll
    for (int ks = 0; ks < 6; ks++)
      qf[ks] = *(const bf16x8*)(qp + ks * 32 + lq * 8);
  }

  f32x4 O[8];
#pragma unroll
  for (int i = 0; i < 8; i++) O[i] = (f32x4)0.f;
  float m_run[4] = {-1e30f, -1e30f, -1e30f, -1e30f};
  float l_run[4] = {0.f, 0.f, 0.f, 0.f};
  const float scale = 0.07216878364870323f;  // 1/sqrt(192)

  for (int t = split; t < nk; t += 2) {
    int k0 = t * TK;
    // ---- stage K: 64 rows x 24 uint4 chunks = 1536 chunks ----
#pragma unroll
    for (int i = 0; i < 6; i++) {
      int c = i * 256 + tid;
      int row = c / 24, off = c % 24;
      *(uint4*)&Ks[row][off * 8] =
          *(const uint4*)(kb + ((size_t)(h * SEQ + k0 + row)) * 192 + off * 8);
    }
    // ---- stage V^T: 128 dims x 8 uint4 chunks = 1024 chunks ----
#pragma unroll
    for (int i = 0; i < 4; i++) {
      int c = i * 256 + tid;
      int d = c >> 3, j = c & 7;
      *(uint4*)&Vs[d][j * 8] =
          *(const uint4*)(vt + ((size_t)(h * 128 + d)) * SEQ + k0 + j * 8);
    }
    __syncthreads();

    // ---- S = Q K^T ----
    f32x4 S[4];
#pragma unroll
    for (int nt = 0; nt < 4; nt++) S[nt] = (f32x4)0.f;
#pragma unroll
    for (int ks = 0; ks < 6; ks++) {
#pragma unroll
      for (int nt = 0; nt < 4; nt++) {
        bf16x8 b = *(const bf16x8*)&Ks[nt * 16 + l16][ks * 32 + lq * 8];
        S[nt] = __builtin_amdgcn_mfma_f32_16x16x32_bf16(qf[ks], b, S[nt], 0, 0, 0);
      }
    }

    // ---- online softmax ----
    bool diag = (k0 == q0);
#pragma unroll
    for (int i = 0; i < 4; i++) {
      int row = q0 + wave * 16 + lq * 4 + i;
      float sv[4];
      float mm = m_run[i];
#pragma unroll
      for (int nt = 0; nt < 4; nt++) {
        float s = S[nt][i] * scale;
        if (diag && (k0 + nt * 16 + l16 > row)) s = -1e30f;
        sv[nt] = s;
        mm = fmaxf(mm, s);
      }
#pragma unroll
      for (int off = 1; off < 16; off <<= 1)
        mm = fmaxf(mm, __shfl_xor(mm, off));
      float alpha = __expf(m_run[i] - mm);
      m_run[i] = mm;
      float ps = 0.f;
      short* prow = &Ps[wave * 16 + lq * 4 + i][l16];
#pragma unroll
      for (int nt = 0; nt < 4; nt++) {
        float p = __expf(sv[nt] - mm);
        ps += p;
        prow[nt * 16] = f2bf(p);
      }
#pragma unroll
      for (int off = 1; off < 16; off <<= 1)
        ps += __shfl_xor(ps, off);
      l_run[i] = l_run[i] * alpha + ps;
#pragma unroll
      for (int nt = 0; nt < 8; nt++) O[nt][i] *= alpha;
    }

    // ---- O += P V ----
#pragma unroll
    for (int kh = 0; kh < 2; kh++) {
      bf16x8 a = *(const bf16x8*)&Ps[wave * 16 + l16][kh * 32 + lq * 8];
#pragma unroll
      for (int nt = 0; nt < 8; nt++) {
        bf16x8 b = *(const bf16x8*)&Vs[nt * 16 + l16][kh * 32 + lq * 8];
        O[nt] = __builtin_amdgcn_mfma_f32_16x16x32_bf16(a, b, O[nt], 0, 0, 0);
      }
    }
    __syncthreads();
  }

  // ---- partial epilogue ----
#pragma unroll
  for (int i = 0; i < 4; i++) {
    int row = q0 + wave * 16 + lq * 4 + i;
    size_t base = ((size_t)(split * N_H + h) * SEQ + row);
    size_t obase = base * 128;
#pragma unroll
    for (int nt = 0; nt < 8; nt++)
      Opart[obase + nt * 16 + l16] = f2bf(O[nt][i]);
    if (l16 == 0) {
      Mpart[base] = m_run[i];
      Lpart[base] = l_run[i];
    }
  }
}

// ---------------------------------------------------------------------------
// merge the two split-K partials -> ao bf16 (s, h*128+d)
// ---------------------------------------------------------------------------
__global__ __launch_bounds__(256) void attn_merge(
    const short* __restrict__ Opart, const float* __restrict__ Mpart,
    const float* __restrict__ Lpart, short* __restrict__ aob) {
  int q0 = blockIdx.x * 16;
  int h = blockIdx.y;
  int tid = threadIdx.x;
#pragma unroll
  for (int i = 0; i < 8; i++) {
    int c = i * 256 + tid;
    int row = q0 + (c >> 7), d = c & 127;
    size_t b0 = (size_t)h * SEQ + row;
    size_t b1 = (size_t)(N_H + h) * SEQ + row;
    float m0 = Mpart[b0], m1 = Mpart[b1];
    float l0 = Lpart[b0], l1 = Lpart[b1];
    float m = fmaxf(m0, m1);
    float a0 = __expf(m0 - m), a1 = __expf(m1 - m);
    float inv = 1.0f / (l0 * a0 + l1 * a1);
    float o0 = bf2f(Opart[b0 * 128 + d]);
    float o1 = bf2f(Opart[b1 * 128 + d]);
    aob[(size_t)row * D_MODEL + h * 128 + d] = f2bf((o0 * a0 + o1 * a1) * inv);
  }
}

// ---------------------------------------------------------------------------
extern "C" void kernel_launch(void* const* d_in, const int* in_sizes, int n_in,
                              void* d_out, int out_size, void* d_ws, size_t ws_size,
                              hipStream_t stream) {
  const float* x      = (const float*)d_in[0];
  // d_in[1] = mask: causal triu, handled structurally — not read.
  const float* w_norm = (const float*)d_in[2];
  const float* w_cq   = (const float*)d_in[3];
  const float* w_q    = (const float*)d_in[4];
  const float* w_qr   = (const float*)d_in[5];
  const float* w_ckv  = (const float*)d_in[6];
  const float* w_k    = (const float*)d_in[7];
  const float* w_kr   = (const float*)d_in[8];
  const float* w_v    = (const float*)d_in[9];
  const float* w_o    = (const float*)d_in[10];
  float* out = (float*)d_out;

  char* ws = (char*)d_ws;
  float* h_f32 = (float*)ws;                       ws += (size_t)SEQ * D_MODEL * 4;   // 16 MiB (aliased by Opart later)
  float* q_r   = (float*)ws;                       ws += (size_t)SEQ * N_H * D_HR * 4; // 8 MiB (aliased by M/Lpart later)
  float* k_r   = (float*)ws;                       ws += (size_t)SEQ * D_HR * 4;
  short* h_bf  = (short*)ws;                       ws += (size_t)SEQ * D_MODEL * 2;
  short* cq_bf = (short*)ws;                       ws += (size_t)SEQ * D_CQ * 2;
  short* ckv_bf= (short*)ws;                       ws += (size_t)SEQ * D_CKV * 2;
  short* qb    = (short*)ws;                       ws += (size_t)N_H * SEQ * 192 * 2;  // [h][s][192]
  short* kb    = (short*)ws;                       ws += (size_t)N_H * SEQ * 192 * 2;
  short* vb    = (short*)ws;                       ws += (size_t)SEQ * D_MODEL * 2;
  short* vt    = (short*)ws;                       ws += (size_t)SEQ * D_MODEL * 2;
  short* ao_bf = (short*)ws;                       ws += (size_t)SEQ * D_MODEL * 2;
  short* wt_cq = (short*)ws;                       ws += (size_t)D_MODEL * D_CQ * 2;
  short* wt_q  = (short*)ws;                       ws += (size_t)D_CQ * N_H * D_H * 2;
  short* wt_qr = (short*)ws;                       ws += (size_t)D_CQ * N_H * D_HR * 2;
  short* wt_ckv= (short*)ws;                       ws += (size_t)D_MODEL * D_CKV * 2;
  short* wt_k  = (short*)ws;                       ws += (size_t)D_CKV * N_H * D_H * 2;
  short* wt_v  = (short*)ws;                       ws += (size_t)D_CKV * D_MODEL * 2;
  short* wt_o  = (short*)ws;                       ws += (size_t)N_H * D_H * D_MODEL * 2;

  // split-K partial buffers alias regions dead by attention time:
  short* Opart = (short*)h_f32;          // 2*16*2048*128*2B = 16 MiB
  float* Mpart = q_r;                    // 2*16*2048*4B = 256 KiB
  float* Lpart = q_r + 2 * N_H * SEQ;    // next 256 KiB (q_r is 8 MiB)

  // weight casts
  cast_wt<<<dim3(D_CQ / 64, D_MODEL / 64), 256, 0, stream>>>(w_cq, wt_cq, D_MODEL, D_CQ);
  cast_wt<<<dim3((N_H * D_H) / 64, D_CQ / 64), 256, 0, stream>>>(w_q, wt_q, D_CQ, N_H * D_H);
  cast_wt<<<dim3((N_H * D_HR) / 64, D_CQ / 64), 256, 0, stream>>>(w_qr, wt_qr, D_CQ, N_H * D_HR);
  cast_wt<<<dim3(D_CKV / 64, D_MODEL / 64), 256, 0, stream>>>(w_ckv, wt_ckv, D_MODEL, D_CKV);
  cast_wt<<<dim3((N_H * D_H) / 64, D_CKV / 64), 256, 0, stream>>>(w_k, wt_k, D_CKV, N_H * D_H);
  cast_wt<<<dim3(D_MODEL / 64, D_CKV / 64), 256, 0, stream>>>(w_v, wt_v, D_CKV, D_MODEL);
  cast_wt<<<dim3(D_MODEL / 64, (N_H * D_H) / 64), 256, 0, stream>>>(w_o, wt_o, N_H * D_H, D_MODEL);

  rmsnorm_kernel<<<SEQ, 256, 0, stream>>>(x, w_norm, h_f32, h_bf);

  // c_q, c_kv (bf16 row-major out)
  gemm_bf16<<<dim3(D_CQ / 128, SEQ / 128), 256, 0, stream>>>(
      h_bf, wt_cq, nullptr, cq_bf, nullptr, SEQ, D_CQ, D_MODEL, 1);
  gemm_bf16<<<dim3(D_CKV / 128, SEQ / 128), 256, 0, stream>>>(
      h_bf, wt_ckv, nullptr, ckv_bf, nullptr, SEQ, D_CKV, D_MODEL, 1);

  // k_r = rope(h @ w_kr) -> kb rope dims (broadcast over heads)
  gemm_f32<<<dim3(D_HR / BN, SEQ / BM), 256, 0, stream>>>(h_f32, w_kr, k_r, nullptr, SEQ, D_HR, D_MODEL);
  rope_k_kernel<<<(SEQ * 32 + 255) / 256, 256, 0, stream>>>(k_r, kb);

  // q_c -> qb (packed), q_r -> f32 then rope -> qb
  gemm_bf16<<<dim3((N_H * D_H) / 128, SEQ / 128), 256, 0, stream>>>(
      cq_bf, wt_q, nullptr, qb, nullptr, SEQ, N_H * D_H, D_CQ, 2);
  gemm_bf16<<<dim3((N_H * D_HR) / 128, SEQ / 128), 256, 0, stream>>>(
      cq_bf, wt_qr, q_r, nullptr, nullptr, SEQ, N_H * D_HR, D_CQ, 0);
  rope_q_kernel<<<(SEQ * N_H * 32 + 255) / 256, 256, 0, stream>>>(q_r, qb);

  // k_c -> kb (packed), v -> vb (bf16 row-major)
  gemm_bf16<<<dim3((N_H * D_H) / 128, SEQ / 128), 256, 0, stream>>>(
      ckv_bf, wt_k, nullptr, kb, nullptr, SEQ, N_H * D_H, D_CKV, 2);
  gemm_bf16<<<dim3(D_MODEL / 128, SEQ / 128), 256, 0, stream>>>(
      ckv_bf, wt_v, nullptr, vb, nullptr, SEQ, D_MODEL, D_CKV, 1);

  cast_v_t<<<dim3(SEQ / 64, N_H), 256, 0, stream>>>(vb, vt);

  attn_mfma<<<dim3(64, N_H), 256, 0, stream>>>(qb, kb, vt, Opart, Mpart, Lpart);
  attn_merge<<<dim3(SEQ / 16, N_H), 256, 0, stream>>>(Opart, Mpart, Lpart, ao_bf);

  // out = ao @ w_o + x
  gemm_bf16<<<dim3(D_MODEL / 128, SEQ / 128), 256, 0, stream>>>(
      ao_bf, wt_o, out, nullptr, x, SEQ, D_MODEL, D_MODEL, 0);
}

// Round 8
// 514.571 us; speedup vs baseline: 14.6717x; 1.2435x over previous
//
#include <hip/hip_runtime.h>
#include <hip/hip_bf16.h>
#include <math.h>

// Problem constants
#define D_MODEL 2048
#define N_H     16
#define D_H     128
#define D_CQ    768
#define D_CKV   512
#define D_HR    64
#define SEQ     2048
#define N_CKVR  640   // 512 (ckv) + 64 (kr) + 64 pad (junk, never read)

typedef short bf16x8 __attribute__((ext_vector_type(8)));
typedef float f32x4  __attribute__((ext_vector_type(4)));

__device__ inline short f2bf(float f) {
  union { float f; unsigned u; } v; v.f = f;
  unsigned r = (v.u + 0x7fff + ((v.u >> 16) & 1)) >> 16;
  return (short)r;
}
__device__ inline float bf2f(short s) {
  union { float f; unsigned u; } v; v.u = ((unsigned)(unsigned short)s) << 16;
  return v.f;
}

// async global->LDS, 16B per lane; lds dest must be wave-uniform base
__device__ inline void gld_lds16(const void* g, void* l) {
#if __has_builtin(__builtin_amdgcn_global_load_lds)
  __builtin_amdgcn_global_load_lds(
      (const __attribute__((address_space(1))) unsigned int*)g,
      (__attribute__((address_space(3))) unsigned int*)l, 16, 0, 0);
#else
  int lane = threadIdx.x & 63;
  *((uint4*)l + lane) = *(const uint4*)g;
#endif
}

// ---------------------------------------------------------------------------
// RMSNorm -> h bf16
// ---------------------------------------------------------------------------
__global__ __launch_bounds__(256) void rmsnorm_kernel(
    const float* __restrict__ x, const float* __restrict__ w,
    short* __restrict__ hb) {
  int row = blockIdx.x;
  int tid = threadIdx.x;
  const float* xr = x + (size_t)row * D_MODEL;
  float ss = 0.f;
  for (int i = tid; i < D_MODEL; i += 256) { float v = xr[i]; ss += v * v; }
  __shared__ float red[256];
  red[tid] = ss;
  __syncthreads();
  for (int s = 128; s > 0; s >>= 1) {
    if (tid < s) red[tid] += red[tid + s];
    __syncthreads();
  }
  float scale = rsqrtf(red[0] / (float)D_MODEL + 1.1920929e-7f);
  short* hbr = hb + (size_t)row * D_MODEL;
  for (int i = tid; i < D_MODEL; i += 256) hbr[i] = f2bf(xr[i] * scale * w[i]);
}

// ---------------------------------------------------------------------------
// Weight cast + transpose: W f32 [K][N] -> Wt bf16 [N][K]
// ---------------------------------------------------------------------------
__global__ __launch_bounds__(256) void cast_wt(
    const float* __restrict__ W, short* __restrict__ Wt, int K, int N) {
  int n0 = blockIdx.x * 64, k0 = blockIdx.y * 64;
  __shared__ short T[64][68];
  int tid = threadIdx.x;
#pragma unroll
  for (int it = 0; it < 16; it++) {
    int idx = it * 256 + tid;
    int r = idx >> 6, c = idx & 63;
    T[c][r] = f2bf(W[(size_t)(k0 + r) * N + n0 + c]);
  }
  __syncthreads();
#pragma unroll
  for (int it = 0; it < 16; it++) {
    int idx = it * 256 + tid;
    int r = idx >> 6, c = idx & 63;
    Wt[(size_t)(n0 + r) * K + k0 + c] = T[r][c];
  }
}

// ---------------------------------------------------------------------------
// MFMA bf16 GEMM: C[M,N] = A[M,K] @ Bt[N,K]^T   (A row stride = lda)
// mode 0: f32 out (+addv); mode 1: bf16 row-major; mode 2: bf16 packed
//         per-head [n>>7][row][192] layout (MLA q/k pack, first 128 dims).
// ---------------------------------------------------------------------------
__global__ __launch_bounds__(256) void gemm_bf16(
    const short* __restrict__ A, const short* __restrict__ Bt,
    float* __restrict__ Cf, short* __restrict__ Cb,
    const float* __restrict__ addv, int M, int N, int K, int lda, int mode) {
  __shared__ short As[128 * 64];
  __shared__ short Bs[128 * 64];
  int tid = threadIdx.x;
  int w = tid >> 6, l = tid & 63;
  int lq = l >> 4, l16 = l & 15;
  int bm = blockIdx.y * 128, bn = blockIdx.x * 128;
  int wr = w >> 1, wc = w & 1;
  int wm0 = wr * 64, wn0 = wc * 64;

  f32x4 acc[4][4];
#pragma unroll
  for (int i = 0; i < 4; i++)
#pragma unroll
    for (int j = 0; j < 4; j++) acc[i][j] = (f32x4)0.f;

  int rsub = (l >> 3);
  int csub = (l & 7) * 8;

  for (int k0 = 0; k0 < K; k0 += 64) {
#pragma unroll
    for (int i = 0; i < 4; i++) {
      int r0 = i * 32 + w * 8;
      gld_lds16(A + (size_t)(bm + r0 + rsub) * lda + k0 + csub, As + r0 * 64);
    }
#pragma unroll
    for (int i = 0; i < 4; i++) {
      int r0 = i * 32 + w * 8;
      gld_lds16(Bt + (size_t)(bn + r0 + rsub) * K + k0 + csub, Bs + r0 * 64);
    }
    __syncthreads();

#pragma unroll
    for (int ks = 0; ks < 2; ks++) {
      bf16x8 af[4], bfr[4];
#pragma unroll
      for (int mt = 0; mt < 4; mt++)
        af[mt] = *(const bf16x8*)&As[(wm0 + mt * 16 + l16) * 64 + ks * 32 + lq * 8];
#pragma unroll
      for (int nt = 0; nt < 4; nt++)
        bfr[nt] = *(const bf16x8*)&Bs[(wn0 + nt * 16 + l16) * 64 + ks * 32 + lq * 8];
#pragma unroll
      for (int mt = 0; mt < 4; mt++)
#pragma unroll
        for (int nt = 0; nt < 4; nt++)
          acc[mt][nt] = __builtin_amdgcn_mfma_f32_16x16x32_bf16(af[mt], bfr[nt], acc[mt][nt], 0, 0, 0);
    }
    __syncthreads();
  }

#pragma unroll
  for (int mt = 0; mt < 4; mt++)
#pragma unroll
    for (int i = 0; i < 4; i++) {
      size_t row = bm + wm0 + mt * 16 + lq * 4 + i;
#pragma unroll
      for (int nt = 0; nt < 4; nt++) {
        int col = bn + wn0 + nt * 16 + l16;
        float v = acc[mt][nt][i];
        if (mode == 0) {
          size_t off = row * N + col;
          if (addv) v += addv[off];
          Cf[off] = v;
        } else if (mode == 1) {
          Cb[row * N + col] = f2bf(v);
        } else {
          Cb[((size_t)(col >> 7) * M + row) * 192 + (col & 127)] = f2bf(v);
        }
      }
    }
}

// ---------------------------------------------------------------------------
// RoPE q: read f32 GEMM output, write rotated bf16 into packed qb.
// qb layout: [h][s][192], rope dims at offset 128.
// ---------------------------------------------------------------------------
__global__ void rope_q_kernel(const float* __restrict__ qr, short* __restrict__ qb) {
  int idx = blockIdx.x * blockDim.x + threadIdx.x;
  if (idx >= SEQ * N_H * 32) return;
  int j = idx & 31;
  int hh = (idx >> 5) & 15;
  int s = idx >> 9;
  const float* p = qr + ((size_t)s * N_H + hh) * 64 + 2 * j;
  float inv = expf(-((float)(2 * j) / 64.0f) * logf(10000.0f));
  float ang = (float)s * inv;
  float c = cosf(ang), sn = sinf(ang);
  float x0 = p[0], x1 = p[1];
  short* q = qb + ((size_t)hh * SEQ + s) * 192 + 128 + 2 * j;
  q[0] = f2bf(x0 * c - x1 * sn);
  q[1] = f2bf(x0 * sn + x1 * c);
}

// ---------------------------------------------------------------------------
// RoPE k: read bf16 cols 512..575 of ckvr buffer, rotate, broadcast to kb.
// ---------------------------------------------------------------------------
__global__ void rope_k_kernel(const short* __restrict__ ckvr, short* __restrict__ kb) {
  int idx = blockIdx.x * blockDim.x + threadIdx.x;
  if (idx >= SEQ * 32) return;
  int j = idx & 31;
  int s = idx >> 5;
  const short* p = ckvr + (size_t)s * N_CKVR + D_CKV + 2 * j;
  float x0 = bf2f(p[0]), x1 = bf2f(p[1]);
  float inv = expf(-((float)(2 * j) / 64.0f) * logf(10000.0f));
  float ang = (float)s * inv;
  float c = cosf(ang), sn = sinf(ang);
  short b0 = f2bf(x0 * c - x1 * sn);
  short b1 = f2bf(x0 * sn + x1 * c);
#pragma unroll
  for (int hh = 0; hh < N_H; hh++) {
    short* k = kb + ((size_t)hh * SEQ + s) * 192 + 128 + 2 * j;
    k[0] = b0;
    k[1] = b1;
  }
}

// ---------------------------------------------------------------------------
// cast_v_t: vb bf16 (s, h*128+d) -> vt bf16 [h][d][s]
// ---------------------------------------------------------------------------
__global__ __launch_bounds__(256) void cast_v_t(
    const short* __restrict__ vb, short* __restrict__ vt) {
  int s0 = blockIdx.x * 64;
  int h = blockIdx.y;
  __shared__ short T[128][72];
  int tid = threadIdx.x;
#pragma unroll
  for (int it = 0; it < 32; it++) {
    int c = it * 256 + tid;
    int r = c >> 7, d = c & 127;
    T[d][r] = vb[(size_t)(s0 + r) * D_MODEL + h * 128 + d];
  }
  __syncthreads();
#pragma unroll
  for (int it = 0; it < 32; it++) {
    int c = it * 256 + tid;
    int d = c >> 6, s = c & 63;
    vt[(size_t)(h * 128 + d) * SEQ + s0 + s] = T[d][s];
  }
}

// ---------------------------------------------------------------------------
// MFMA bf16 flash attention, 2-way split-K. Block = (head, q-tile, split).
// ---------------------------------------------------------------------------
#define TQ 64
#define TK 64

__global__ __launch_bounds__(256) void attn_mfma(
    const short* __restrict__ qb, const short* __restrict__ kb,
    const short* __restrict__ vt, short* __restrict__ Opart,
    float* __restrict__ Mpart, float* __restrict__ Lpart) {
  int h = blockIdx.y;
  int bx = blockIdx.x;
  int qt = 31 - (bx >> 1);      // heavy tiles first (LPT)
  int split = bx & 1;
  int q0 = qt * TQ;
  int nk = qt + 1;
  int tid = threadIdx.x;
  int wave = tid >> 6, lane = tid & 63;
  int lq = lane >> 4, l16 = lane & 15;

  __shared__ short Ks[TK][200];   // [key][192 dims]
  __shared__ short Vs[128][72];   // [dim][64 keys]
  __shared__ short Ps[TQ][72];    // [query][64 keys] — wave-private rows

  // ---- Q fragments (bf16 direct) ----
  bf16x8 qf[6];
  {
    const short* qp = qb + ((size_t)h * SEQ + q0 + wave * 16 + l16) * 192;
#pragma unroll
    for (int ks = 0; ks < 6; ks++)
      qf[ks] = *(const bf16x8*)(qp + ks * 32 + lq * 8);
  }

  f32x4 O[8];
#pragma unroll
  for (int i = 0; i < 8; i++) O[i] = (f32x4)0.f;
  float m_run[4] = {-1e30f, -1e30f, -1e30f, -1e30f};
  float l_run[4] = {0.f, 0.f, 0.f, 0.f};
  const float scale = 0.07216878364870323f;  // 1/sqrt(192)

  for (int t = split; t < nk; t += 2) {
    int k0 = t * TK;
    // ---- stage K: 64 rows x 24 uint4 chunks = 1536 chunks ----
#pragma unroll
    for (int i = 0; i < 6; i++) {
      int c = i * 256 + tid;
      int row = c / 24, off = c % 24;
      *(uint4*)&Ks[row][off * 8] =
          *(const uint4*)(kb + ((size_t)(h * SEQ + k0 + row)) * 192 + off * 8);
    }
    // ---- stage V^T: 128 dims x 8 uint4 chunks = 1024 chunks ----
#pragma unroll
    for (int i = 0; i < 4; i++) {
      int c = i * 256 + tid;
      int d = c >> 3, j = c & 7;
      *(uint4*)&Vs[d][j * 8] =
          *(const uint4*)(vt + ((size_t)(h * 128 + d)) * SEQ + k0 + j * 8);
    }
    __syncthreads();

    // ---- S = Q K^T ----
    f32x4 S[4];
#pragma unroll
    for (int nt = 0; nt < 4; nt++) S[nt] = (f32x4)0.f;
#pragma unroll
    for (int ks = 0; ks < 6; ks++) {
#pragma unroll
      for (int nt = 0; nt < 4; nt++) {
        bf16x8 b = *(const bf16x8*)&Ks[nt * 16 + l16][ks * 32 + lq * 8];
        S[nt] = __builtin_amdgcn_mfma_f32_16x16x32_bf16(qf[ks], b, S[nt], 0, 0, 0);
      }
    }

    // ---- online softmax ----
    bool diag = (k0 == q0);
#pragma unroll
    for (int i = 0; i < 4; i++) {
      int row = q0 + wave * 16 + lq * 4 + i;
      float sv[4];
      float mm = m_run[i];
#pragma unroll
      for (int nt = 0; nt < 4; nt++) {
        float s = S[nt][i] * scale;
        if (diag && (k0 + nt * 16 + l16 > row)) s = -1e30f;
        sv[nt] = s;
        mm = fmaxf(mm, s);
      }
#pragma unroll
      for (int off = 1; off < 16; off <<= 1)
        mm = fmaxf(mm, __shfl_xor(mm, off));
      float alpha = __expf(m_run[i] - mm);
      m_run[i] = mm;
      float ps = 0.f;
      short* prow = &Ps[wave * 16 + lq * 4 + i][l16];
#pragma unroll
      for (int nt = 0; nt < 4; nt++) {
        float p = __expf(sv[nt] - mm);
        ps += p;
        prow[nt * 16] = f2bf(p);
      }
#pragma unroll
      for (int off = 1; off < 16; off <<= 1)
        ps += __shfl_xor(ps, off);
      l_run[i] = l_run[i] * alpha + ps;
#pragma unroll
      for (int nt = 0; nt < 8; nt++) O[nt][i] *= alpha;
    }

    // ---- O += P V ----
#pragma unroll
    for (int kh = 0; kh < 2; kh++) {
      bf16x8 a = *(const bf16x8*)&Ps[wave * 16 + l16][kh * 32 + lq * 8];
#pragma unroll
      for (int nt = 0; nt < 8; nt++) {
        bf16x8 b = *(const bf16x8*)&Vs[nt * 16 + l16][kh * 32 + lq * 8];
        O[nt] = __builtin_amdgcn_mfma_f32_16x16x32_bf16(a, b, O[nt], 0, 0, 0);
      }
    }
    __syncthreads();
  }

  // ---- partial epilogue ----
#pragma unroll
  for (int i = 0; i < 4; i++) {
    int row = q0 + wave * 16 + lq * 4 + i;
    size_t base = ((size_t)(split * N_H + h) * SEQ + row);
    size_t obase = base * 128;
#pragma unroll
    for (int nt = 0; nt < 8; nt++)
      Opart[obase + nt * 16 + l16] = f2bf(O[nt][i]);
    if (l16 == 0) {
      Mpart[base] = m_run[i];
      Lpart[base] = l_run[i];
    }
  }
}

// ---------------------------------------------------------------------------
// merge the two split-K partials -> ao bf16 (s, h*128+d)
// ---------------------------------------------------------------------------
__global__ __launch_bounds__(256) void attn_merge(
    const short* __restrict__ Opart, const float* __restrict__ Mpart,
    const float* __restrict__ Lpart, short* __restrict__ aob) {
  int q0 = blockIdx.x * 16;
  int h = blockIdx.y;
  int tid = threadIdx.x;
#pragma unroll
  for (int i = 0; i < 8; i++) {
    int c = i * 256 + tid;
    int row = q0 + (c >> 7), d = c & 127;
    size_t b0 = (size_t)h * SEQ + row;
    size_t b1 = (size_t)(N_H + h) * SEQ + row;
    float m0 = Mpart[b0], m1 = Mpart[b1];
    float l0 = Lpart[b0], l1 = Lpart[b1];
    float m = fmaxf(m0, m1);
    float a0 = __expf(m0 - m), a1 = __expf(m1 - m);
    float inv = 1.0f / (l0 * a0 + l1 * a1);
    float o0 = bf2f(Opart[b0 * 128 + d]);
    float o1 = bf2f(Opart[b1 * 128 + d]);
    aob[(size_t)row * D_MODEL + h * 128 + d] = f2bf((o0 * a0 + o1 * a1) * inv);
  }
}

// ---------------------------------------------------------------------------
extern "C" void kernel_launch(void* const* d_in, const int* in_sizes, int n_in,
                              void* d_out, int out_size, void* d_ws, size_t ws_size,
                              hipStream_t stream) {
  const float* x      = (const float*)d_in[0];
  // d_in[1] = mask: causal triu, handled structurally — not read.
  const float* w_norm = (const float*)d_in[2];
  const float* w_cq   = (const float*)d_in[3];
  const float* w_q    = (const float*)d_in[4];
  const float* w_qr   = (const float*)d_in[5];
  const float* w_ckv  = (const float*)d_in[6];
  const float* w_k    = (const float*)d_in[7];
  const float* w_kr   = (const float*)d_in[8];
  const float* w_v    = (const float*)d_in[9];
  const float* w_o    = (const float*)d_in[10];
  float* out = (float*)d_out;

  char* ws = (char*)d_ws;
  short* h_bf   = (short*)ws;  ws += (size_t)SEQ * D_MODEL * 2;
  short* cq_bf  = (short*)ws;  ws += (size_t)SEQ * D_CQ * 2;
  short* ckvr_bf= (short*)ws;  ws += (size_t)SEQ * N_CKVR * 2;   // [s][640]: 0..511 ckv, 512..575 kr, 576..639 junk
  short* qb     = (short*)ws;  ws += (size_t)N_H * SEQ * 192 * 2; // [h][s][192]
  short* kb     = (short*)ws;  ws += (size_t)N_H * SEQ * 192 * 2;
  short* vb     = (short*)ws;  ws += (size_t)SEQ * D_MODEL * 2;
  short* vt     = (short*)ws;  ws += (size_t)SEQ * D_MODEL * 2;
  short* ao_bf  = (short*)ws;  ws += (size_t)SEQ * D_MODEL * 2;
  short* Opart  = (short*)ws;  ws += (size_t)2 * N_H * SEQ * 128 * 2;
  float* q_r    = (float*)ws;  ws += (size_t)SEQ * N_H * D_HR * 4;  // f32; aliased by M/Lpart after rope_q
  short* wt_cq  = (short*)ws;  ws += (size_t)D_MODEL * D_CQ * 2;
  short* wt_q   = (short*)ws;  ws += (size_t)D_CQ * N_H * D_H * 2;
  short* wt_qr  = (short*)ws;  ws += (size_t)D_CQ * N_H * D_HR * 2;
  short* wt_ckvr= (short*)ws;  ws += (size_t)D_MODEL * N_CKVR * 2; // [640][2048]
  short* wt_k   = (short*)ws;  ws += (size_t)D_CKV * N_H * D_H * 2;
  short* wt_v   = (short*)ws;  ws += (size_t)D_CKV * D_MODEL * 2;
  short* wt_o   = (short*)ws;  ws += (size_t)N_H * D_H * D_MODEL * 2;

  float* Mpart = q_r;                    // 256 KiB
  float* Lpart = q_r + 2 * N_H * SEQ;    // next 256 KiB (q_r region is 8 MiB)

  // weight casts
  cast_wt<<<dim3(D_CQ / 64, D_MODEL / 64), 256, 0, stream>>>(w_cq, wt_cq, D_MODEL, D_CQ);
  cast_wt<<<dim3((N_H * D_H) / 64, D_CQ / 64), 256, 0, stream>>>(w_q, wt_q, D_CQ, N_H * D_H);
  cast_wt<<<dim3((N_H * D_HR) / 64, D_CQ / 64), 256, 0, stream>>>(w_qr, wt_qr, D_CQ, N_H * D_HR);
  cast_wt<<<dim3(D_CKV / 64, D_MODEL / 64), 256, 0, stream>>>(w_ckv, wt_ckvr, D_MODEL, D_CKV);
  cast_wt<<<dim3(D_HR / 64, D_MODEL / 64), 256, 0, stream>>>(w_kr, wt_ckvr + (size_t)D_CKV * D_MODEL, D_MODEL, D_HR);
  cast_wt<<<dim3((N_H * D_H) / 64, D_CKV / 64), 256, 0, stream>>>(w_k, wt_k, D_CKV, N_H * D_H);
  cast_wt<<<dim3(D_MODEL / 64, D_CKV / 64), 256, 0, stream>>>(w_v, wt_v, D_CKV, D_MODEL);
  cast_wt<<<dim3(D_MODEL / 64, (N_H * D_H) / 64), 256, 0, stream>>>(w_o, wt_o, N_H * D_H, D_MODEL);

  rmsnorm_kernel<<<SEQ, 256, 0, stream>>>(x, w_norm, h_bf);

  // c_q (bf16), c_kv|k_r fused (bf16, N=640)
  gemm_bf16<<<dim3(D_CQ / 128, SEQ / 128), 256, 0, stream>>>(
      h_bf, wt_cq, nullptr, cq_bf, nullptr, SEQ, D_CQ, D_MODEL, D_MODEL, 1);
  gemm_bf16<<<dim3(N_CKVR / 128, SEQ / 128), 256, 0, stream>>>(
      h_bf, wt_ckvr, nullptr, ckvr_bf, nullptr, SEQ, N_CKVR, D_MODEL, D_MODEL, 1);

  rope_k_kernel<<<(SEQ * 32 + 255) / 256, 256, 0, stream>>>(ckvr_bf, kb);

  // q_c -> qb (packed), q_r -> f32 then rope -> qb
  gemm_bf16<<<dim3((N_H * D_H) / 128, SEQ / 128), 256, 0, stream>>>(
      cq_bf, wt_q, nullptr, qb, nullptr, SEQ, N_H * D_H, D_CQ, D_CQ, 2);
  gemm_bf16<<<dim3((N_H * D_HR) / 128, SEQ / 128), 256, 0, stream>>>(
      cq_bf, wt_qr, q_r, nullptr, nullptr, SEQ, N_H * D_HR, D_CQ, D_CQ, 0);
  rope_q_kernel<<<(SEQ * N_H * 32 + 255) / 256, 256, 0, stream>>>(q_r, qb);

  // k_c -> kb (packed), v -> vb (bf16 row-major); A = ckvr with lda=640
  gemm_bf16<<<dim3((N_H * D_H) / 128, SEQ / 128), 256, 0, stream>>>(
      ckvr_bf, wt_k, nullptr, kb, nullptr, SEQ, N_H * D_H, D_CKV, N_CKVR, 2);
  gemm_bf16<<<dim3(D_MODEL / 128, SEQ / 128), 256, 0, stream>>>(
      ckvr_bf, wt_v, nullptr, vb, nullptr, SEQ, D_MODEL, D_CKV, N_CKVR, 1);

  cast_v_t<<<dim3(SEQ / 64, N_H), 256, 0, stream>>>(vb, vt);

  attn_mfma<<<dim3(64, N_H), 256, 0, stream>>>(qb, kb, vt, Opart, Mpart, Lpart);
  attn_merge<<<dim3(SEQ / 16, N_H), 256, 0, stream>>>(Opart, Mpart, Lpart, ao_bf);

  // out = ao @ w_o + x
  gemm_bf16<<<dim3(D_MODEL / 128, SEQ / 128), 256, 0, stream>>>(
      ao_bf, wt_o, out, nullptr, x, SEQ, D_MODEL, D_MODEL, D_MODEL, 0);
}

// Round 9
// 412.482 us; speedup vs baseline: 18.3030x; 1.2475x over previous
//
#include <hip/hip_runtime.h>
#include <hip/hip_bf16.h>
#include <math.h>

// Problem constants
#define D_MODEL 2048
#define N_H     16
#define D_H     128
#define D_CQ    768
#define D_CKV   512
#define D_HR    64
#define SEQ     2048
#define N_ACT1  1408  // 768 (cq) + 512 (ckv) + 64 (kr) + 64 pad (junk)
#define NSPLIT  4

typedef short bf16x8 __attribute__((ext_vector_type(8)));
typedef float f32x4  __attribute__((ext_vector_type(4)));

__device__ inline short f2bf(float f) {
  union { float f; unsigned u; } v; v.f = f;
  unsigned r = (v.u + 0x7fff + ((v.u >> 16) & 1)) >> 16;
  return (short)r;
}
__device__ inline float bf2f(short s) {
  union { float f; unsigned u; } v; v.u = ((unsigned)(unsigned short)s) << 16;
  return v.f;
}

// async global->LDS, 16B per lane; lds dest must be wave-uniform base
__device__ inline void gld_lds16(const void* g, void* l) {
#if __has_builtin(__builtin_amdgcn_global_load_lds)
  __builtin_amdgcn_global_load_lds(
      (const __attribute__((address_space(1))) unsigned int*)g,
      (__attribute__((address_space(3))) unsigned int*)l, 16, 0, 0);
#else
  int lane = threadIdx.x & 63;
  *((uint4*)l + lane) = *(const uint4*)g;
#endif
}

// ---------------------------------------------------------------------------
// RMSNorm -> h bf16
// ---------------------------------------------------------------------------
__global__ __launch_bounds__(256) void rmsnorm_kernel(
    const float* __restrict__ x, const float* __restrict__ w,
    short* __restrict__ hb) {
  int row = blockIdx.x;
  int tid = threadIdx.x;
  const float* xr = x + (size_t)row * D_MODEL;
  float ss = 0.f;
  for (int i = tid; i < D_MODEL; i += 256) { float v = xr[i]; ss += v * v; }
  __shared__ float red[256];
  red[tid] = ss;
  __syncthreads();
  for (int s = 128; s > 0; s >>= 1) {
    if (tid < s) red[tid] += red[tid + s];
    __syncthreads();
  }
  float scale = rsqrtf(red[0] / (float)D_MODEL + 1.1920929e-7f);
  short* hbr = hb + (size_t)row * D_MODEL;
  for (int i = tid; i < D_MODEL; i += 256) hbr[i] = f2bf(xr[i] * scale * w[i]);
}

// ---------------------------------------------------------------------------
// Fused weight cast+transpose: 8 jobs, W f32 [K][N] -> Wt bf16 [N][K].
// One launch; each block resolves its job from the prefix table.
// ---------------------------------------------------------------------------
struct CastJobs {
  const float* src[8];
  short* dst[8];
  int K[8];
  int pref[9];   // prefix sums of tile counts; tiles_x = N/64 implied by pref
  int nx[8];     // tiles in n direction
};

__global__ __launch_bounds__(256) void cast_all(CastJobs J) {
  int bid = blockIdx.x;
  int j = 0;
#pragma unroll
  for (int t = 0; t < 8; t++)
    if (bid >= J.pref[t + 1]) j = t + 1;
  int lid = bid - J.pref[j];
  int nx = J.nx[j];
  int ty = lid / nx, tx = lid - ty * nx;
  int n0 = tx * 64, k0 = ty * 64;
  int K = J.K[j];
  const float* W = J.src[j];
  short* Wt = J.dst[j];
  int Nfull = nx * 64;

  __shared__ short T[64][68];
  int tid = threadIdx.x;
#pragma unroll
  for (int it = 0; it < 16; it++) {
    int idx = it * 256 + tid;
    int r = idx >> 6, c = idx & 63;
    T[c][r] = f2bf(W[(size_t)(k0 + r) * Nfull + n0 + c]);
  }
  __syncthreads();
#pragma unroll
  for (int it = 0; it < 16; it++) {
    int idx = it * 256 + tid;
    int r = idx >> 6, c = idx & 63;
    Wt[(size_t)(n0 + r) * K + k0 + c] = T[r][c];
  }
}

// ---------------------------------------------------------------------------
// MFMA bf16 GEMM: C[M,N] = A[M,K] @ Bt[N,K]^T   (A row stride = lda)
// mode 0: f32 out (+addv)
// mode 1: bf16 row-major Cb [M][N]
// mode 3: MLA q-pack: col<2048 -> qb packed [h][s][192] (first 128 dims);
//         col>=2048 -> RoPE rotate (shfl_xor pair) -> qb dims 128..191.
// mode 4: MLA k/v: col<2048 -> kb packed; col>=2048 -> Cb2 row-major [s][2048].
// ---------------------------------------------------------------------------
__global__ __launch_bounds__(256) void gemm_bf16(
    const short* __restrict__ A, const short* __restrict__ Bt,
    float* __restrict__ Cf, short* __restrict__ Cb, short* __restrict__ Cb2,
    const float* __restrict__ addv, int M, int N, int K, int lda, int mode) {
  __shared__ short As[128 * 64];
  __shared__ short Bs[128 * 64];
  int tid = threadIdx.x;
  int w = tid >> 6, l = tid & 63;
  int lq = l >> 4, l16 = l & 15;
  int bm = blockIdx.y * 128, bn = blockIdx.x * 128;
  int wr = w >> 1, wc = w & 1;
  int wm0 = wr * 64, wn0 = wc * 64;

  f32x4 acc[4][4];
#pragma unroll
  for (int i = 0; i < 4; i++)
#pragma unroll
    for (int j = 0; j < 4; j++) acc[i][j] = (f32x4)0.f;

  int rsub = (l >> 3);
  int csub = (l & 7) * 8;

  for (int k0 = 0; k0 < K; k0 += 64) {
#pragma unroll
    for (int i = 0; i < 4; i++) {
      int r0 = i * 32 + w * 8;
      gld_lds16(A + (size_t)(bm + r0 + rsub) * lda + k0 + csub, As + r0 * 64);
    }
#pragma unroll
    for (int i = 0; i < 4; i++) {
      int r0 = i * 32 + w * 8;
      gld_lds16(Bt + (size_t)(bn + r0 + rsub) * K + k0 + csub, Bs + r0 * 64);
    }
    __syncthreads();

#pragma unroll
    for (int ks = 0; ks < 2; ks++) {
      bf16x8 af[4], bfr[4];
#pragma unroll
      for (int mt = 0; mt < 4; mt++)
        af[mt] = *(const bf16x8*)&As[(wm0 + mt * 16 + l16) * 64 + ks * 32 + lq * 8];
#pragma unroll
      for (int nt = 0; nt < 4; nt++)
        bfr[nt] = *(const bf16x8*)&Bs[(wn0 + nt * 16 + l16) * 64 + ks * 32 + lq * 8];
#pragma unroll
      for (int mt = 0; mt < 4; mt++)
#pragma unroll
        for (int nt = 0; nt < 4; nt++)
          acc[mt][nt] = __builtin_amdgcn_mfma_f32_16x16x32_bf16(af[mt], bfr[nt], acc[mt][nt], 0, 0, 0);
    }
    __syncthreads();
  }

#pragma unroll
  for (int mt = 0; mt < 4; mt++)
#pragma unroll
    for (int i = 0; i < 4; i++) {
      int row = bm + wm0 + mt * 16 + lq * 4 + i;
#pragma unroll
      for (int nt = 0; nt < 4; nt++) {
        int col = bn + wn0 + nt * 16 + l16;
        float v = acc[mt][nt][i];
        if (mode == 0) {
          size_t off = (size_t)row * N + col;
          if (addv) v += addv[off];
          Cf[off] = v;
        } else if (mode == 1) {
          Cb[(size_t)row * N + col] = f2bf(v);
        } else if (mode == 3) {
          if (col < 2048) {
            Cb[((size_t)(col >> 7) * M + row) * 192 + (col & 127)] = f2bf(v);
          } else {
            int cc = col - 2048;
            int hh = cc >> 6, dd = cc & 63;
            float partner = __shfl_xor(v, 1);
            float inv = __expf(-((float)(dd & ~1) / 64.0f) * 9.210340372f); // ln 10000
            float ang = (float)row * inv;
            float c = __cosf(ang), s = __sinf(ang);
            float res = ((l16 & 1) == 0) ? (v * c - partner * s)
                                         : (partner * s + v * c);
            Cb[((size_t)hh * M + row) * 192 + 128 + dd] = f2bf(res);
          }
        } else {  // mode 4
          if (col < 2048) {
            Cb[((size_t)(col >> 7) * M + row) * 192 + (col & 127)] = f2bf(v);
          } else {
            Cb2[(size_t)row * D_MODEL + (col - 2048)] = f2bf(v);
          }
        }
      }
    }
}

// ---------------------------------------------------------------------------
// RoPE k: read bf16 cols 1280..1343 of act1, rotate, broadcast to kb heads.
// ---------------------------------------------------------------------------
__global__ void rope_k_kernel(const short* __restrict__ act1, short* __restrict__ kb) {
  int idx = blockIdx.x * blockDim.x + threadIdx.x;
  if (idx >= SEQ * 32) return;
  int j = idx & 31;
  int s = idx >> 5;
  const short* p = act1 + (size_t)s * N_ACT1 + 1280 + 2 * j;
  float x0 = bf2f(p[0]), x1 = bf2f(p[1]);
  float inv = __expf(-((float)(2 * j) / 64.0f) * 9.210340372f);
  float ang = (float)s * inv;
  float c = __cosf(ang), sn = __sinf(ang);
  short b0 = f2bf(x0 * c - x1 * sn);
  short b1 = f2bf(x0 * sn + x1 * c);
#pragma unroll
  for (int hh = 0; hh < N_H; hh++) {
    short* k = kb + ((size_t)hh * SEQ + s) * 192 + 128 + 2 * j;
    k[0] = b0;
    k[1] = b1;
  }
}

// ---------------------------------------------------------------------------
// cast_v_t: vb bf16 (s, h*128+d) -> vt bf16 [h][d][s]
// ---------------------------------------------------------------------------
__global__ __launch_bounds__(256) void cast_v_t(
    const short* __restrict__ vb, short* __restrict__ vt) {
  int s0 = blockIdx.x * 64;
  int h = blockIdx.y;
  __shared__ short T[128][72];
  int tid = threadIdx.x;
#pragma unroll
  for (int it = 0; it < 32; it++) {
    int c = it * 256 + tid;
    int r = c >> 7, d = c & 127;
    T[d][r] = vb[(size_t)(s0 + r) * D_MODEL + h * 128 + d];
  }
  __syncthreads();
#pragma unroll
  for (int it = 0; it < 32; it++) {
    int c = it * 256 + tid;
    int d = c >> 6, s = c & 63;
    vt[(size_t)(h * 128 + d) * SEQ + s0 + s] = T[d][s];
  }
}

// ---------------------------------------------------------------------------
// MFMA bf16 flash attention, 4-way split-K. Block = (head, q-tile, split).
// ---------------------------------------------------------------------------
#define TQ 64
#define TK 64

__global__ __launch_bounds__(256) void attn_mfma(
    const short* __restrict__ qb, const short* __restrict__ kb,
    const short* __restrict__ vt, short* __restrict__ Opart,
    float* __restrict__ Mpart, float* __restrict__ Lpart) {
  int h = blockIdx.y;
  int bx = blockIdx.x;
  int qt = 31 - (bx >> 2);      // heavy tiles first (LPT)
  int split = bx & 3;
  int q0 = qt * TQ;
  int nk = qt + 1;
  int tid = threadIdx.x;
  int wave = tid >> 6, lane = tid & 63;
  int lq = lane >> 4, l16 = lane & 15;

  __shared__ short Ks[TK][200];   // [key][192 dims]
  __shared__ short Vs[128][72];   // [dim][64 keys]
  __shared__ short Ps[TQ][72];    // [query][64 keys] — wave-private rows

  // ---- Q fragments ----
  bf16x8 qf[6];
  {
    const short* qp = qb + ((size_t)h * SEQ + q0 + wave * 16 + l16) * 192;
#pragma unroll
    for (int ks = 0; ks < 6; ks++)
      qf[ks] = *(const bf16x8*)(qp + ks * 32 + lq * 8);
  }

  f32x4 O[8];
#pragma unroll
  for (int i = 0; i < 8; i++) O[i] = (f32x4)0.f;
  float m_run[4] = {-1e30f, -1e30f, -1e30f, -1e30f};
  float l_run[4] = {0.f, 0.f, 0.f, 0.f};
  const float scale = 0.07216878364870323f;  // 1/sqrt(192)

  for (int t = split; t < nk; t += NSPLIT) {
    int k0 = t * TK;
    // ---- stage K: 64 rows x 24 uint4 chunks = 1536 chunks ----
#pragma unroll
    for (int i = 0; i < 6; i++) {
      int c = i * 256 + tid;
      int row = c / 24, off = c % 24;
      *(uint4*)&Ks[row][off * 8] =
          *(const uint4*)(kb + ((size_t)(h * SEQ + k0 + row)) * 192 + off * 8);
    }
    // ---- stage V^T: 128 dims x 8 uint4 chunks ----
#pragma unroll
    for (int i = 0; i < 4; i++) {
      int c = i * 256 + tid;
      int d = c >> 3, j = c & 7;
      *(uint4*)&Vs[d][j * 8] =
          *(const uint4*)(vt + ((size_t)(h * 128 + d)) * SEQ + k0 + j * 8);
    }
    __syncthreads();

    // ---- S = Q K^T ----
    f32x4 S[4];
#pragma unroll
    for (int nt = 0; nt < 4; nt++) S[nt] = (f32x4)0.f;
#pragma unroll
    for (int ks = 0; ks < 6; ks++) {
#pragma unroll
      for (int nt = 0; nt < 4; nt++) {
        bf16x8 b = *(const bf16x8*)&Ks[nt * 16 + l16][ks * 32 + lq * 8];
        S[nt] = __builtin_amdgcn_mfma_f32_16x16x32_bf16(qf[ks], b, S[nt], 0, 0, 0);
      }
    }

    // ---- online softmax ----
    bool diag = (k0 == q0);
#pragma unroll
    for (int i = 0; i < 4; i++) {
      int row = q0 + wave * 16 + lq * 4 + i;
      float sv[4];
      float mm = m_run[i];
#pragma unroll
      for (int nt = 0; nt < 4; nt++) {
        float s = S[nt][i] * scale;
        if (diag && (k0 + nt * 16 + l16 > row)) s = -1e30f;
        sv[nt] = s;
        mm = fmaxf(mm, s);
      }
#pragma unroll
      for (int off = 1; off < 16; off <<= 1)
        mm = fmaxf(mm, __shfl_xor(mm, off));
      float alpha = __expf(m_run[i] - mm);
      m_run[i] = mm;
      float ps = 0.f;
      short* prow = &Ps[wave * 16 + lq * 4 + i][l16];
#pragma unroll
      for (int nt = 0; nt < 4; nt++) {
        float p = __expf(sv[nt] - mm);
        ps += p;
        prow[nt * 16] = f2bf(p);
      }
#pragma unroll
      for (int off = 1; off < 16; off <<= 1)
        ps += __shfl_xor(ps, off);
      l_run[i] = l_run[i] * alpha + ps;
#pragma unroll
      for (int nt = 0; nt < 8; nt++) O[nt][i] *= alpha;
    }

    // ---- O += P V ----
#pragma unroll
    for (int kh = 0; kh < 2; kh++) {
      bf16x8 a = *(const bf16x8*)&Ps[wave * 16 + l16][kh * 32 + lq * 8];
#pragma unroll
      for (int nt = 0; nt < 8; nt++) {
        bf16x8 b = *(const bf16x8*)&Vs[nt * 16 + l16][kh * 32 + lq * 8];
        O[nt] = __builtin_amdgcn_mfma_f32_16x16x32_bf16(a, b, O[nt], 0, 0, 0);
      }
    }
    __syncthreads();
  }

  // ---- partial epilogue (always written, even for empty splits) ----
#pragma unroll
  for (int i = 0; i < 4; i++) {
    int row = q0 + wave * 16 + lq * 4 + i;
    size_t base = ((size_t)(split * N_H + h) * SEQ + row);
    size_t obase = base * 128;
#pragma unroll
    for (int nt = 0; nt < 8; nt++)
      Opart[obase + nt * 16 + l16] = f2bf(O[nt][i]);
    if (l16 == 0) {
      Mpart[base] = m_run[i];
      Lpart[base] = l_run[i];
    }
  }
}

// ---------------------------------------------------------------------------
// merge the NSPLIT split-K partials -> ao bf16 (s, h*128+d)
// ---------------------------------------------------------------------------
__global__ __launch_bounds__(256) void attn_merge(
    const short* __restrict__ Opart, const float* __restrict__ Mpart,
    const float* __restrict__ Lpart, short* __restrict__ aob) {
  int q0 = blockIdx.x * 16;
  int h = blockIdx.y;
  int tid = threadIdx.x;
#pragma unroll
  for (int i = 0; i < 8; i++) {
    int c = i * 256 + tid;
    int row = q0 + (c >> 7), d = c & 127;
    size_t base[NSPLIT];
    float mv[NSPLIT], lv[NSPLIT];
    float m = -1e30f;
#pragma unroll
    for (int p = 0; p < NSPLIT; p++) {
      base[p] = (size_t)(p * N_H + h) * SEQ + row;
      mv[p] = Mpart[base[p]];
      lv[p] = Lpart[base[p]];
      m = fmaxf(m, mv[p]);
    }
    float denom = 0.f, num = 0.f;
#pragma unroll
    for (int p = 0; p < NSPLIT; p++) {
      float a = __expf(mv[p] - m);
      denom += lv[p] * a;
      num += bf2f(Opart[base[p] * 128 + d]) * a;
    }
    aob[(size_t)row * D_MODEL + h * 128 + d] = f2bf(num / denom);
  }
}

// ---------------------------------------------------------------------------
extern "C" void kernel_launch(void* const* d_in, const int* in_sizes, int n_in,
                              void* d_out, int out_size, void* d_ws, size_t ws_size,
                              hipStream_t stream) {
  const float* x      = (const float*)d_in[0];
  // d_in[1] = mask: causal triu, handled structurally — not read.
  const float* w_norm = (const float*)d_in[2];
  const float* w_cq   = (const float*)d_in[3];
  const float* w_q    = (const float*)d_in[4];
  const float* w_qr   = (const float*)d_in[5];
  const float* w_ckv  = (const float*)d_in[6];
  const float* w_k    = (const float*)d_in[7];
  const float* w_kr   = (const float*)d_in[8];
  const float* w_v    = (const float*)d_in[9];
  const float* w_o    = (const float*)d_in[10];
  float* out = (float*)d_out;

  char* ws = (char*)d_ws;
  short* h_bf  = (short*)ws;  ws += (size_t)SEQ * D_MODEL * 2;
  short* act1  = (short*)ws;  ws += (size_t)SEQ * N_ACT1 * 2;   // [s][1408]: cq|ckv|kr|junk
  short* qb    = (short*)ws;  ws += (size_t)N_H * SEQ * 192 * 2;
  short* kb    = (short*)ws;  ws += (size_t)N_H * SEQ * 192 * 2;
  short* vb    = (short*)ws;  ws += (size_t)SEQ * D_MODEL * 2;
  short* vt    = (short*)ws;  ws += (size_t)SEQ * D_MODEL * 2;
  short* ao_bf = (short*)ws;  ws += (size_t)SEQ * D_MODEL * 2;
  short* Opart = (short*)ws;  ws += (size_t)NSPLIT * N_H * SEQ * 128 * 2;
  float* Mpart = (float*)ws;  ws += (size_t)NSPLIT * N_H * SEQ * 4;
  float* Lpart = (float*)ws;  ws += (size_t)NSPLIT * N_H * SEQ * 4;
  short* WT1   = (short*)ws;  ws += (size_t)N_ACT1 * D_MODEL * 2;   // [1408][2048]
  short* WT2   = (short*)ws;  ws += (size_t)3072 * D_CQ * 2;        // [3072][768]
  short* WT3   = (short*)ws;  ws += (size_t)4096 * D_CKV * 2;       // [4096][512]
  short* WTO   = (short*)ws;  ws += (size_t)D_MODEL * D_MODEL * 2;  // [2048][2048]

  // ---- fused weight casts (8 jobs, 1 launch) ----
  CastJobs J;
  J.src[0] = w_cq;  J.dst[0] = WT1;                              J.K[0] = D_MODEL; J.nx[0] = D_CQ / 64;
  J.src[1] = w_ckv; J.dst[1] = WT1 + (size_t)768 * D_MODEL;      J.K[1] = D_MODEL; J.nx[1] = D_CKV / 64;
  J.src[2] = w_kr;  J.dst[2] = WT1 + (size_t)1280 * D_MODEL;     J.K[2] = D_MODEL; J.nx[2] = D_HR / 64;
  J.src[3] = w_q;   J.dst[3] = WT2;                              J.K[3] = D_CQ;    J.nx[3] = 2048 / 64;
  J.src[4] = w_qr;  J.dst[4] = WT2 + (size_t)2048 * D_CQ;        J.K[4] = D_CQ;    J.nx[4] = 1024 / 64;
  J.src[5] = w_k;   J.dst[5] = WT3;                              J.K[5] = D_CKV;   J.nx[5] = 2048 / 64;
  J.src[6] = w_v;   J.dst[6] = WT3 + (size_t)2048 * D_CKV;       J.K[6] = D_CKV;   J.nx[6] = 2048 / 64;
  J.src[7] = w_o;   J.dst[7] = WTO;                              J.K[7] = D_MODEL; J.nx[7] = 2048 / 64;
  int pref = 0;
  for (int j = 0; j < 8; j++) {
    J.pref[j] = pref;
    pref += J.nx[j] * (J.K[j] / 64);
  }
  J.pref[8] = pref;  // 2784
  cast_all<<<pref, 256, 0, stream>>>(J);

  rmsnorm_kernel<<<SEQ, 256, 0, stream>>>(x, w_norm, h_bf);

  // GEMM1: act1 = h @ [w_cq | w_ckv | w_kr | junk]   (N=1408)
  gemm_bf16<<<dim3(N_ACT1 / 128, SEQ / 128), 256, 0, stream>>>(
      h_bf, WT1, nullptr, act1, nullptr, nullptr, SEQ, N_ACT1, D_MODEL, D_MODEL, 1);

  rope_k_kernel<<<(SEQ * 32 + 255) / 256, 256, 0, stream>>>(act1, kb);

  // GEMM2: qb = c_q @ [w_q | w_qr]  (N=3072, rope fused in epilogue)
  gemm_bf16<<<dim3(3072 / 128, SEQ / 128), 256, 0, stream>>>(
      act1, WT2, nullptr, qb, nullptr, nullptr, SEQ, 3072, D_CQ, N_ACT1, 3);

  // GEMM3: kb|vb = c_kv @ [w_k | w_v]  (N=4096)
  gemm_bf16<<<dim3(4096 / 128, SEQ / 128), 256, 0, stream>>>(
      act1 + 768, WT3, nullptr, kb, vb, nullptr, SEQ, 4096, D_CKV, N_ACT1, 4);

  cast_v_t<<<dim3(SEQ / 64, N_H), 256, 0, stream>>>(vb, vt);

  attn_mfma<<<dim3(32 * NSPLIT, N_H), 256, 0, stream>>>(qb, kb, vt, Opart, Mpart, Lpart);
  attn_merge<<<dim3(SEQ / 16, N_H), 256, 0, stream>>>(Opart, Mpart, Lpart, ao_bf);

  // out = ao @ w_o + x
  gemm_bf16<<<dim3(D_MODEL / 128, SEQ / 128), 256, 0, stream>>>(
      ao_bf, WTO, out, nullptr, nullptr, x, SEQ, D_MODEL, D_MODEL, D_MODEL, 0);
}